// Round 8
// baseline (940.706 us; speedup 1.0000x reference)
//
#include <hip/hip_runtime.h>

// ---------------- constants ----------------
#define CUTOFF_F     0.35f
#define PI_F         3.14159265358979323846f
#define SQRT3_F      1.7320508075688772f
#define INV_SQRT3_F  0.5773502691896258f
#define INV_SQRT_S_F 0.17677669529663687f   // 1/sqrt(32)
#define INV_SQRT_V_F 0.25f                  // 1/sqrt(16)
#define A_SC_F       0.14433756729740643f   // 1/sqrt(48)

// ws layout (floats): [0..12) M matrix, [16..) node state double buffers
#define OFF_M    0
#define OFF_NODE 16

// M[c][k] = (1/256) * Y[:,c] . dirs[:,k];  Y = [1, sqrt3*dirs]
__global__ void mmat_kernel(const float* __restrict__ dirs, float* __restrict__ wf) {
  int t = threadIdx.x;
  if (t >= 12) return;
  int c = t / 3, k = t - c * 3;
  float acc = 0.f;
  for (int p = 0; p < 256; ++p) {
    float dk = dirs[p * 3 + k];
    acc += (c == 0) ? dk : dirs[p * 3 + (c - 1)] * dk;
  }
  wf[OFF_M + t] = acc * ((c == 0) ? (1.0f / 256.0f) : (SQRT3_F / 256.0f));
}

// s0[n][w] = (x[n,0:3] @ Wins)[w]/sqrt3 ; v0[n][u][k] = x[n,3+k]*Winv[u]
__global__ __launch_bounds__(256) void node_init_kernel(
    const float* __restrict__ x, const float* __restrict__ wins,
    const float* __restrict__ winv,
    float* __restrict__ s0, float* __restrict__ v0, int N)
{
  int t = blockIdx.x * 256 + threadIdx.x;
  int n = t / 80; int slot = t - n * 80;
  if (n >= N) return;
  if (slot < 32) {
    float acc = 0.f;
    #pragma unroll
    for (int d = 0; d < 3; ++d) acc += x[n * 6 + d] * wins[d * 32 + slot];
    s0[n * 32 + slot] = acc * INV_SQRT3_F;
  } else {
    int j = slot - 32; int u = j / 3; int k = j - u * 3;
    v0[n * 48 + j] = x[n * 6 + 3 + k] * winv[u];
  }
}

// self-connection: sn = (sc @ Wsc_s)*inv_s ; vn = (vc x Wsc_v)*inv_v  (full overwrite)
__global__ __launch_bounds__(256) void selfmix_kernel(
    const float* __restrict__ sc, const float* __restrict__ vc,
    float* __restrict__ sn, float* __restrict__ vn,
    const float* __restrict__ wscs, const float* __restrict__ wscv,
    int layer, int N)
{
  int t = blockIdx.x * 256 + threadIdx.x;
  int n = t / 80; int slot = t - n * 80;
  if (n >= N) return;
  if (slot < 32) {
    const float* W = wscs + layer * 1024;
    float acc = 0.f;
    #pragma unroll
    for (int u = 0; u < 32; ++u) acc += sc[n * 32 + u] * W[u * 32 + slot];
    sn[n * 32 + slot] = acc * INV_SQRT_S_F;
  } else {
    int j = slot - 32; int w = j / 3; int k = j - w * 3;
    const float* W = wscv + layer * 256;
    float acc = 0.f;
    #pragma unroll
    for (int u = 0; u < 16; ++u) acc += vc[n * 48 + u * 3 + k] * W[u * 16 + w];
    vn[n * 48 + j] = acc * INV_SQRT_V_F;
  }
}

// ---------------- per-edge kernel: 128 edges/block (2 per lane), w-split ------
// Each broadcast weight read now feeds 2 edges -> LDS read instr/edge halved.
// Two passes: A/C (s_j resident) over W1||W3 tiles, B/D (v_j resident) over
// W2||W4 tiles. Cross-wave exchange carries ms/mv (80 f/edge) instead of raw
// A..D (128 f/edge): wave q's w-slots of A..D are exactly the u-slots of ms/mv.
// LDS: sH 16.5KB + sW 12KB + sX 40.5KB = 69KB -> 2 blocks/CU.
__global__ __launch_bounds__(256, 2) void edge_kernel(
    const int* __restrict__ ei, const float* __restrict__ ed,
    const float* __restrict__ esh,
    const float* __restrict__ sc, const float* __restrict__ vc,
    float* __restrict__ sn, float* __restrict__ vn,
    const float* __restrict__ wr1, const float* __restrict__ br1,
    const float* __restrict__ wr2, const float* __restrict__ br2,
    const float* __restrict__ wpgs, const float* __restrict__ wpgv,
    const float* __restrict__ wlos, const float* __restrict__ wlov,
    int layer, int E, int N)
{
  __shared__ float sH[128 * 33];   // hext per edge (stride 33, conflict-free)
  __shared__ float sW[3072];       // weight tile (2 rows of W1||W3 or W2||W4)
  __shared__ float sX[128 * 81];   // ms 0..31 | mv 32..79 ; later gs | gv

  const int tid  = threadIdx.x;
  const int lane = tid & 63;
  const int q    = tid >> 6;
  const int wq8  = q * 8;
  const int wq4  = q * 4;
  const int e0   = blockIdx.x * 128 + lane;
  const int e1   = e0 + 64;
  const bool ok0 = e0 < E, ok1 = e1 < E;
  const int eL0  = ok0 ? e0 : E - 1;
  const int eL1  = ok1 ? e1 : E - 1;
  int sn0 = ei[eL0];     sn0 = (sn0 < 0) ? 0 : (sn0 >= N ? N - 1 : sn0);
  int sn1 = ei[eL1];     sn1 = (sn1 < 0) ? 0 : (sn1 >= N ? N - 1 : sn1);
  int dn0 = ei[E + eL0]; dn0 = (dn0 < 0) ? 0 : (dn0 >= N ? N - 1 : dn0);
  int dn1 = ei[E + eL1]; dn1 = (dn1 < 0) ? 0 : (dn1 >= N ? N - 1 : dn1);
  const float y00 = esh[eL0*4+0], y0x = esh[eL0*4+1], y0y = esh[eL0*4+2], y0z = esh[eL0*4+3];
  const float y10 = esh[eL1*4+0], y1x = esh[eL1*4+1], y1y = esh[eL1*4+2], y1z = esh[eL1*4+3];

  // ---- h for both edges: wave q fills slots [wq8, wq8+8); bias slot by q==0 --
  {
    const float d0 = ed[eL0], d1 = ed[eL1];
    const float inv_w = 12.0f / CUTOFF_F;
    float cut0 = (d0 < CUTOFF_F) ? 0.5f * (__cosf(d0 * (PI_F / CUTOFF_F)) + 1.0f) : 0.0f;
    float cut1 = (d1 < CUTOFF_F) ? 0.5f * (__cosf(d1 * (PI_F / CUTOFF_F)) + 1.0f) : 0.0f;
    float rb0[6], rb1[6];
    #pragma unroll
    for (int r = 0; r < 6; ++r) {
      float z0 = (d0 - 0.07f * (float)r) * inv_w;
      float z1 = (d1 - 0.07f * (float)r) * inv_w;
      rb0[r] = __expf(-0.5f * z0 * z0) * cut0;
      rb1[r] = __expf(-0.5f * z1 * z1) * cut1;
    }
    const float* W1p = wr1 + layer * 192;
    const float* B1p = br1 + layer * 32;
    #pragma unroll
    for (int jj = 0; jj < 8; ++jj) {
      const int j = wq8 + jj;
      float z0 = B1p[j], z1 = z0;
      #pragma unroll
      for (int r = 0; r < 6; ++r) {
        const float wv = W1p[r * 32 + j];
        z0 += rb0[r] * wv; z1 += rb1[r] * wv;
      }
      sH[lane * 33 + j]        = z0 / (1.0f + __expf(-z0));
      sH[(lane + 64) * 33 + j] = z1 / (1.0f + __expf(-z1));
    }
    if (q == 0) { sH[lane * 33 + 32] = 1.0f; sH[(lane + 64) * 33 + 32] = 1.0f; }
  }

  const float* wrbase = wr2 + (size_t)layer * 32 * 2304;
  const float* brrow  = br2 + (size_t)layer * 2304;

  // ================= pass 1: A/C with s_j resident =================
  float sj0[32], sj1[32];
  { const float4* p0 = (const float4*)(sc + (size_t)sn0 * 32);
    const float4* p1 = (const float4*)(sc + (size_t)sn1 * 32);
    #pragma unroll
    for (int m = 0; m < 8; ++m) {
      float4 a = p0[m]; sj0[m*4]=a.x; sj0[m*4+1]=a.y; sj0[m*4+2]=a.z; sj0[m*4+3]=a.w;
      float4 b = p1[m]; sj1[m*4]=b.x; sj1[m*4+1]=b.y; sj1[m*4+2]=b.z; sj1[m*4+3]=b.w;
    } }
  float A0[8], A1[8], C0[4], C1[4];
  #pragma unroll
  for (int i = 0; i < 8; ++i) { A0[i] = 0.f; A1[i] = 0.f; }
  #pragma unroll
  for (int i = 0; i < 4; ++i) { C0[i] = 0.f; C1[i] = 0.f; }

  for (int t = 0; t < 17; ++t) {
    __syncthreads();  // previous tile fully consumed (and sH ready at t==0)
    // stage tile: rows of [W1(1024 f) || W3(512 f)] -> 384 f4 per row
    if (t < 16) {
      const int c0 = t * 2;
      #pragma unroll
      for (int ii = 0; ii < 3; ++ii) {
        const int i = ii * 256 + tid;           // 0..767
        const int r = i / 384; const int c4 = i - r * 384;
        const float4* gp = (const float4*)(wrbase + (size_t)(c0 + r) * 2304);
        ((float4*)sW)[i] = gp[(c4 < 256) ? c4 : c4 + 128];  // W3 src f4 384..
      }
    } else {
      #pragma unroll
      for (int ii = 0; ii < 2; ++ii) {
        const int i = ii * 256 + tid;
        if (i < 384) {
          const float4* gp = (const float4*)brrow;
          ((float4*)sW)[i] = gp[(i < 256) ? i : i + 128];
        }
      }
    }
    __syncthreads();
    const int nr = (t < 16) ? 2 : 1;
    for (int r = 0; r < nr; ++r) {
      const int c = (t < 16) ? t * 2 + r : 32;
      const float h0 = sH[lane * 33 + c];
      const float h1 = sH[(lane + 64) * 33 + c];
      const float* w1 = sW + r * 1536 + wq8;          // u stride 32
      const float* w3 = sW + r * 1536 + 1024 + wq4;   // u stride 16
      #pragma unroll
      for (int u = 0; u < 32; ++u) {
        const float p0 = h0 * sj0[u], p1 = h1 * sj1[u];
        const float4 a0 = *(const float4*)(w1 + u * 32);
        const float4 a1 = *(const float4*)(w1 + u * 32 + 4);
        A0[0] += p0*a0.x; A0[1] += p0*a0.y; A0[2] += p0*a0.z; A0[3] += p0*a0.w;
        A0[4] += p0*a1.x; A0[5] += p0*a1.y; A0[6] += p0*a1.z; A0[7] += p0*a1.w;
        A1[0] += p1*a0.x; A1[1] += p1*a0.y; A1[2] += p1*a0.z; A1[3] += p1*a0.w;
        A1[4] += p1*a1.x; A1[5] += p1*a1.y; A1[6] += p1*a1.z; A1[7] += p1*a1.w;
        const float4 cc = *(const float4*)(w3 + u * 16);
        C0[0] += p0*cc.x; C0[1] += p0*cc.y; C0[2] += p0*cc.z; C0[3] += p0*cc.w;
        C1[0] += p1*cc.x; C1[1] += p1*cc.y; C1[2] += p1*cc.z; C1[3] += p1*cc.w;
      }
    }
  }

  // ================= pass 2: B/D with v_j resident =================
  float vj0[48], vj1[48];
  { const float4* p0 = (const float4*)(vc + (size_t)sn0 * 48);
    const float4* p1 = (const float4*)(vc + (size_t)sn1 * 48);
    #pragma unroll
    for (int m = 0; m < 12; ++m) {
      float4 a = p0[m]; vj0[m*4]=a.x; vj0[m*4+1]=a.y; vj0[m*4+2]=a.z; vj0[m*4+3]=a.w;
      float4 b = p1[m]; vj1[m*4]=b.x; vj1[m*4+1]=b.y; vj1[m*4+2]=b.z; vj1[m*4+3]=b.w;
    } }
  float vd0[16], vd1[16];
  #pragma unroll
  for (int u = 0; u < 16; ++u) {
    vd0[u] = vj0[u*3]*y0x + vj0[u*3+1]*y0y + vj0[u*3+2]*y0z;
    vd1[u] = vj1[u*3]*y1x + vj1[u*3+1]*y1y + vj1[u*3+2]*y1z;
  }
  float B0[8], B1[8], D0[12], D1[12];
  #pragma unroll
  for (int i = 0; i < 8; ++i) { B0[i] = 0.f; B1[i] = 0.f; }
  #pragma unroll
  for (int i = 0; i < 12; ++i) { D0[i] = 0.f; D1[i] = 0.f; }

  for (int t = 0; t < 17; ++t) {
    __syncthreads();
    // stage tile: rows of [W2(512 f) || W4(256 f)] -> 192 f4 per row
    if (t < 16) {
      const int c0 = t * 2;
      #pragma unroll
      for (int ii = 0; ii < 2; ++ii) {
        const int i = ii * 256 + tid;
        if (i < 384) {
          const int r = i / 192; const int c4 = i - r * 192;
          const float4* gp = (const float4*)(wrbase + (size_t)(c0 + r) * 2304);
          ((float4*)sW)[i] = gp[(c4 < 128) ? 256 + c4 : 512 + (c4 - 128)];
        }
      }
    } else {
      const int i = tid;
      if (i < 192) {
        const float4* gp = (const float4*)brrow;
        ((float4*)sW)[i] = gp[(i < 128) ? 256 + i : 512 + (i - 128)];
      }
    }
    __syncthreads();
    const int nr = (t < 16) ? 2 : 1;
    for (int r = 0; r < nr; ++r) {
      const int c = (t < 16) ? t * 2 + r : 32;
      const float h0 = sH[lane * 33 + c];
      const float h1 = sH[(lane + 64) * 33 + c];
      const float* w2 = sW + r * 768 + wq8;          // u stride 32
      const float* w4 = sW + r * 768 + 512 + wq4;    // u stride 16
      #pragma unroll
      for (int u = 0; u < 16; ++u) {
        const float pb0 = h0 * vd0[u], pb1 = h1 * vd1[u];
        const float4 b0 = *(const float4*)(w2 + u * 32);
        const float4 b1 = *(const float4*)(w2 + u * 32 + 4);
        B0[0] += pb0*b0.x; B0[1] += pb0*b0.y; B0[2] += pb0*b0.z; B0[3] += pb0*b0.w;
        B0[4] += pb0*b1.x; B0[5] += pb0*b1.y; B0[6] += pb0*b1.z; B0[7] += pb0*b1.w;
        B1[0] += pb1*b0.x; B1[1] += pb1*b0.y; B1[2] += pb1*b0.z; B1[3] += pb1*b0.w;
        B1[4] += pb1*b1.x; B1[5] += pb1*b1.y; B1[6] += pb1*b1.z; B1[7] += pb1*b1.w;
        const float va0 = h0*vj0[u*3], vb0 = h0*vj0[u*3+1], vk0 = h0*vj0[u*3+2];
        const float va1 = h1*vj1[u*3], vb1 = h1*vj1[u*3+1], vk1 = h1*vj1[u*3+2];
        const float4 d4 = *(const float4*)(w4 + u * 16);
        D0[0] += va0*d4.x; D0[1]  += vb0*d4.x; D0[2]  += vk0*d4.x;
        D0[3] += va0*d4.y; D0[4]  += vb0*d4.y; D0[5]  += vk0*d4.y;
        D0[6] += va0*d4.z; D0[7]  += vb0*d4.z; D0[8]  += vk0*d4.z;
        D0[9] += va0*d4.w; D0[10] += vb0*d4.w; D0[11] += vk0*d4.w;
        D1[0] += va1*d4.x; D1[1]  += vb1*d4.x; D1[2]  += vk1*d4.x;
        D1[3] += va1*d4.y; D1[4]  += vb1*d4.y; D1[5]  += vk1*d4.y;
        D1[6] += va1*d4.z; D1[7]  += vb1*d4.z; D1[8]  += vk1*d4.z;
        D1[9] += va1*d4.w; D1[10] += vb1*d4.w; D1[11] += vk1*d4.w;
      }
    }
  }

  // ---- ms/mv into sX: wave q's w-slots of A..D are its u-slots of ms/mv ----
  #pragma unroll
  for (int i = 0; i < 8; ++i) {
    sX[lane * 81 + wq8 + i]        = A_SC_F * (y00 * A0[i] + INV_SQRT3_F * B0[i]);
    sX[(lane + 64) * 81 + wq8 + i] = A_SC_F * (y10 * A1[i] + INV_SQRT3_F * B1[i]);
  }
  #pragma unroll
  for (int i = 0; i < 4; ++i) {
    const int u = wq4 + i;
    sX[lane * 81 + 32 + u*3 + 0] = A_SC_F * (C0[i] * y0x + y00 * D0[i*3 + 0]);
    sX[lane * 81 + 32 + u*3 + 1] = A_SC_F * (C0[i] * y0y + y00 * D0[i*3 + 1]);
    sX[lane * 81 + 32 + u*3 + 2] = A_SC_F * (C0[i] * y0z + y00 * D0[i*3 + 2]);
    sX[(lane+64) * 81 + 32 + u*3 + 0] = A_SC_F * (C1[i] * y1x + y10 * D1[i*3 + 0]);
    sX[(lane+64) * 81 + 32 + u*3 + 1] = A_SC_F * (C1[i] * y1y + y10 * D1[i*3 + 1]);
    sX[(lane+64) * 81 + 32 + u*3 + 2] = A_SC_F * (C1[i] * y1z + y10 * D1[i*3 + 2]);
  }
  __syncthreads();  // full ms/mv visible

  // ---- pg phase (w-split across waves, both edges per lane) ----
  float ps0[8], ps1[8], pt0[4], pt1[4];
  #pragma unroll
  for (int i = 0; i < 8; ++i) { ps0[i] = 0.f; ps1[i] = 0.f; }
  #pragma unroll
  for (int i = 0; i < 4; ++i) { pt0[i] = 0.f; pt1[i] = 0.f; }
  {
    const float* Wp = wpgs + layer * 1536;
    #pragma unroll
    for (int u = 0; u < 32; ++u) {
      const float m0 = sX[lane * 81 + u];
      const float m1 = sX[(lane + 64) * 81 + u];
      #pragma unroll
      for (int jj = 0; jj < 8; ++jj) {
        const float wv = Wp[u * 48 + wq8 + jj];
        ps0[jj] += m0 * wv; ps1[jj] += m1 * wv;
      }
      #pragma unroll
      for (int wi = 0; wi < 4; ++wi) {
        const float wv = Wp[u * 48 + 32 + wq4 + wi];
        pt0[wi] += m0 * wv; pt1[wi] += m1 * wv;
      }
    }
  }
  float pv0[12], pv1[12];
  #pragma unroll
  for (int i = 0; i < 12; ++i) { pv0[i] = 0.f; pv1[i] = 0.f; }
  {
    const float* Wp = wpgv + layer * 256;
    #pragma unroll
    for (int u = 0; u < 16; ++u) {
      const float a0 = sX[lane*81 + 32 + u*3 + 0];
      const float a1 = sX[lane*81 + 32 + u*3 + 1];
      const float a2 = sX[lane*81 + 32 + u*3 + 2];
      const float b0 = sX[(lane+64)*81 + 32 + u*3 + 0];
      const float b1 = sX[(lane+64)*81 + 32 + u*3 + 1];
      const float b2 = sX[(lane+64)*81 + 32 + u*3 + 2];
      #pragma unroll
      for (int wi = 0; wi < 4; ++wi) {
        const float wv = Wp[u * 16 + wq4 + wi];
        pv0[wi*3+0] += a0*wv; pv0[wi*3+1] += a1*wv; pv0[wi*3+2] += a2*wv;
        pv1[wi*3+0] += b0*wv; pv1[wi*3+1] += b1*wv; pv1[wi*3+2] += b2*wv;
      }
    }
  }
  __syncthreads();  // all pg reads of sX done

  // ---- gates into exclusive sX slots: gs 0..31 | gv 32..79 ----
  #pragma unroll
  for (int jj = 0; jj < 8; ++jj) {
    const float t0 = ps0[jj] * INV_SQRT_S_F;
    const float t1 = ps1[jj] * INV_SQRT_S_F;
    sX[lane * 81 + wq8 + jj]        = t0 / (1.0f + __expf(-t0));
    sX[(lane + 64) * 81 + wq8 + jj] = t1 / (1.0f + __expf(-t1));
  }
  #pragma unroll
  for (int wi = 0; wi < 4; ++wi) {
    const float g0 = 1.0f / (1.0f + __expf(-pt0[wi] * INV_SQRT_S_F));
    const float g1 = 1.0f / (1.0f + __expf(-pt1[wi] * INV_SQRT_S_F));
    #pragma unroll
    for (int k = 0; k < 3; ++k) {
      sX[lane * 81 + 32 + (wq4 + wi)*3 + k]        = g0 * pv0[wi*3+k] * INV_SQRT_V_F;
      sX[(lane + 64) * 81 + 32 + (wq4 + wi)*3 + k] = g1 * pv1[wi*3+k] * INV_SQRT_V_F;
    }
  }
  __syncthreads();  // gates visible

  // ---- o = g @ Wlo (w-split), scatter with HW fp32 atomics ----
  float os0[8], os1[8];
  #pragma unroll
  for (int i = 0; i < 8; ++i) { os0[i] = 0.f; os1[i] = 0.f; }
  {
    const float* Wp = wlos + layer * 1024;
    #pragma unroll
    for (int u = 0; u < 32; ++u) {
      const float g0 = sX[lane * 81 + u];
      const float g1 = sX[(lane + 64) * 81 + u];
      #pragma unroll
      for (int wi = 0; wi < 8; ++wi) {
        const float wv = Wp[u * 32 + wq8 + wi];
        os0[wi] += g0 * wv; os1[wi] += g1 * wv;
      }
    }
  }
  float ov0[12], ov1[12];
  #pragma unroll
  for (int i = 0; i < 12; ++i) { ov0[i] = 0.f; ov1[i] = 0.f; }
  {
    const float* Wp = wlov + layer * 256;
    #pragma unroll
    for (int u = 0; u < 16; ++u) {
      const float a0 = sX[lane*81 + 32 + u*3 + 0];
      const float a1 = sX[lane*81 + 32 + u*3 + 1];
      const float a2 = sX[lane*81 + 32 + u*3 + 2];
      const float b0 = sX[(lane+64)*81 + 32 + u*3 + 0];
      const float b1 = sX[(lane+64)*81 + 32 + u*3 + 1];
      const float b2 = sX[(lane+64)*81 + 32 + u*3 + 2];
      #pragma unroll
      for (int wi = 0; wi < 4; ++wi) {
        const float wv = Wp[u * 16 + wq4 + wi];
        ov0[wi*3+0] += a0*wv; ov0[wi*3+1] += a1*wv; ov0[wi*3+2] += a2*wv;
        ov1[wi*3+0] += b0*wv; ov1[wi*3+1] += b1*wv; ov1[wi*3+2] += b2*wv;
      }
    }
  }
  if (ok0) {
    float* sd = sn + (size_t)dn0 * 32 + wq8;
    #pragma unroll
    for (int wi = 0; wi < 8; ++wi) unsafeAtomicAdd(&sd[wi], os0[wi] * INV_SQRT_S_F);
    float* vd = vn + (size_t)dn0 * 48 + wq4 * 3;
    #pragma unroll
    for (int j = 0; j < 12; ++j) unsafeAtomicAdd(&vd[j], ov0[j] * INV_SQRT_V_F);
  }
  if (ok1) {
    float* sd = sn + (size_t)dn1 * 32 + wq8;
    #pragma unroll
    for (int wi = 0; wi < 8; ++wi) unsafeAtomicAdd(&sd[wi], os1[wi] * INV_SQRT_S_F);
    float* vd = vn + (size_t)dn1 * 48 + wq4 * 3;
    #pragma unroll
    for (int j = 0; j < 12; ++j) unsafeAtomicAdd(&vd[j], ov1[j] * INV_SQRT_V_F);
  }
}

// out[n,k] = coeffs[n] @ M  (rho @ dirs collapsed analytically) — FP32 OUTPUT
__global__ __launch_bounds__(256) void final_kernel(
    const float* __restrict__ s0, const float* __restrict__ v0,
    const float* __restrict__ wos, const float* __restrict__ wov,
    const float* __restrict__ wf, float* __restrict__ out, int N)
{
  int n = blockIdx.x * 256 + threadIdx.x;
  if (n >= N) return;
  float cs = 0.f;
  #pragma unroll
  for (int u = 0; u < 32; ++u) cs += s0[n * 32 + u] * wos[u];
  cs *= INV_SQRT_S_F;
  float cv0 = 0.f, cv1 = 0.f, cv2 = 0.f;
  #pragma unroll
  for (int u = 0; u < 16; ++u) {
    const float wv = wov[u];
    cv0 += v0[n * 48 + u * 3 + 0] * wv;
    cv1 += v0[n * 48 + u * 3 + 1] * wv;
    cv2 += v0[n * 48 + u * 3 + 2] * wv;
  }
  cv0 *= INV_SQRT_V_F; cv1 *= INV_SQRT_V_F; cv2 *= INV_SQRT_V_F;
  #pragma unroll
  for (int k = 0; k < 3; ++k) {
    out[n * 3 + k] = cs  * wf[OFF_M + k]
                   + cv0 * wf[OFF_M + 3 + k]
                   + cv1 * wf[OFF_M + 6 + k]
                   + cv2 * wf[OFF_M + 9 + k];
  }
}

extern "C" void kernel_launch(void* const* d_in, const int* in_sizes, int n_in,
                              void* d_out, int out_size, void* d_ws, size_t ws_size,
                              hipStream_t stream)
{
  (void)n_in; (void)out_size; (void)ws_size;
  const float* x    = (const float*)d_in[0];
  const int*   ei   = (const int*)d_in[1];
  const float* ed   = (const float*)d_in[2];
  const float* esh  = (const float*)d_in[3];
  const float* dirs = (const float*)d_in[4];
  const float* wins = (const float*)d_in[5];
  const float* winv = (const float*)d_in[6];
  const float* wscs = (const float*)d_in[7];
  const float* wscv = (const float*)d_in[8];
  const float* wr1  = (const float*)d_in[9];
  const float* br1  = (const float*)d_in[10];
  const float* wr2  = (const float*)d_in[11];
  const float* br2  = (const float*)d_in[12];
  const float* wpgs = (const float*)d_in[13];
  const float* wpgv = (const float*)d_in[14];
  const float* wlos = (const float*)d_in[15];
  const float* wlov = (const float*)d_in[16];
  const float* wos  = (const float*)d_in[17];
  const float* wov  = (const float*)d_in[18];

  const int N = in_sizes[0] / 6;
  const int E = in_sizes[1] / 2;

  float* wf = (float*)d_ws;
  float* s0 = wf + OFF_NODE;
  float* v0 = s0 + (size_t)N * 32;
  float* s1 = v0 + (size_t)N * 48;
  float* v1 = s1 + (size_t)N * 32;

  const int nodeBlocks = (N * 80 + 255) / 256;
  const int edgeBlocks = (E + 127) / 128;
  const int finBlocks  = (N + 255) / 256;

  mmat_kernel<<<1, 64, 0, stream>>>(dirs, wf);
  node_init_kernel<<<nodeBlocks, 256, 0, stream>>>(x, wins, winv, s0, v0, N);

  // layer 0: s0/v0 -> s1/v1
  selfmix_kernel<<<nodeBlocks, 256, 0, stream>>>(s0, v0, s1, v1, wscs, wscv, 0, N);
  edge_kernel<<<edgeBlocks, 256, 0, stream>>>(ei, ed, esh, s0, v0, s1, v1,
      wr1, br1, wr2, br2, wpgs, wpgv, wlos, wlov, 0, E, N);
  // layer 1: s1/v1 -> s0/v0
  selfmix_kernel<<<nodeBlocks, 256, 0, stream>>>(s1, v1, s0, v0, wscs, wscv, 1, N);
  edge_kernel<<<edgeBlocks, 256, 0, stream>>>(ei, ed, esh, s1, v1, s0, v0,
      wr1, br1, wr2, br2, wpgs, wpgv, wlos, wlov, 1, E, N);

  final_kernel<<<finBlocks, 256, 0, stream>>>(s0, v0, wos, wov, wf,
      (float*)d_out, N);
}

// Round 9
// 794.422 us; speedup vs baseline: 1.1841x; 1.1841x over previous
//
#include <hip/hip_runtime.h>

// ---------------- constants ----------------
#define CUTOFF_F     0.35f
#define PI_F         3.14159265358979323846f
#define SQRT3_F      1.7320508075688772f
#define INV_SQRT3_F  0.5773502691896258f
#define INV_SQRT_S_F 0.17677669529663687f   // 1/sqrt(32)
#define INV_SQRT_V_F 0.25f                  // 1/sqrt(16)
#define A_SC_F       0.14433756729740643f   // 1/sqrt(48)

// ws layout (floats): [0..12) M | fragHi | fragLo | node buffers
#define OFF_M      0
#define OFF_FRAGHI 16        // 147456 ushort = 73728 floats
#define OFF_FRAGLO 73744     // 147456 ushort
#define OFF_NODE   147472

typedef __attribute__((ext_vector_type(8))) short bshort8;
typedef __attribute__((ext_vector_type(4))) float f32x4;

static __device__ __forceinline__ float b2f(unsigned short u) {
  union { unsigned int i; float f; } x; x.i = ((unsigned int)u) << 16; return x.f;
}
static __device__ __forceinline__ unsigned short f2b(float f) {
  union { float f; unsigned int i; } x; x.f = f;
  unsigned int i = x.i;
  return (unsigned short)((i + 0x7FFFu + ((i >> 16) & 1u)) >> 16);
}
static __device__ __forceinline__ f32x4 mfma3(bshort8 ah, bshort8 al, bshort8 bh, bshort8 bl) {
  f32x4 z = {0.f, 0.f, 0.f, 0.f};
  z = __builtin_amdgcn_mfma_f32_16x16x32_bf16(al, bh, z, 0, 0, 0);
  z = __builtin_amdgcn_mfma_f32_16x16x32_bf16(ah, bl, z, 0, 0, 0);
  z = __builtin_amdgcn_mfma_f32_16x16x32_bf16(ah, bh, z, 0, 0, 0);
  return z;
}

// pack Wr2 into MFMA B-fragments, compensated bf16 (hi + lo residual)
// frag[layer][tile t][lane][i] = W[c = (lane>>4)*8+i][j = 16t + (lane&15)]
__global__ __launch_bounds__(256) void fragpack_kernel(
    const float* __restrict__ wr2, unsigned short* __restrict__ fhi,
    unsigned short* __restrict__ flo)
{
  int idx = blockIdx.x * 256 + threadIdx.x;
  if (idx >= 147456) return;
  int i    = idx & 7;
  int lane = (idx >> 3) & 63;
  int t    = (idx >> 9) & 143;        // 144 tiles -> fits since (idx>>9) < 288
  int layer = idx / (144 * 512);
  if (((idx >> 9) % 144) != t) t = (idx >> 9) % 144;   // safe decode
  int c = (lane >> 4) * 8 + i;
  int j = t * 16 + (lane & 15);
  float w = wr2[((size_t)(layer * 32 + c)) * 2304 + j];
  unsigned short h = f2b(w);
  fhi[idx] = h;
  flo[idx] = f2b(w - b2f(h));
}

// M[c][k] = (1/256) * Y[:,c] . dirs[:,k];  Y = [1, sqrt3*dirs]
__global__ void mmat_kernel(const float* __restrict__ dirs, float* __restrict__ wf) {
  int t = threadIdx.x;
  if (t >= 12) return;
  int c = t / 3, k = t - c * 3;
  float acc = 0.f;
  for (int p = 0; p < 256; ++p) {
    float dk = dirs[p * 3 + k];
    acc += (c == 0) ? dk : dirs[p * 3 + (c - 1)] * dk;
  }
  wf[OFF_M + t] = acc * ((c == 0) ? (1.0f / 256.0f) : (SQRT3_F / 256.0f));
}

__global__ __launch_bounds__(256) void node_init_kernel(
    const float* __restrict__ x, const float* __restrict__ wins,
    const float* __restrict__ winv,
    float* __restrict__ s0, float* __restrict__ v0, int N)
{
  int t = blockIdx.x * 256 + threadIdx.x;
  int n = t / 80; int slot = t - n * 80;
  if (n >= N) return;
  if (slot < 32) {
    float acc = 0.f;
    #pragma unroll
    for (int d = 0; d < 3; ++d) acc += x[n * 6 + d] * wins[d * 32 + slot];
    s0[n * 32 + slot] = acc * INV_SQRT3_F;
  } else {
    int j = slot - 32; int u = j / 3; int k = j - u * 3;
    v0[n * 48 + j] = x[n * 6 + 3 + k] * winv[u];
  }
}

__global__ __launch_bounds__(256) void selfmix_kernel(
    const float* __restrict__ sc, const float* __restrict__ vc,
    float* __restrict__ sn, float* __restrict__ vn,
    const float* __restrict__ wscs, const float* __restrict__ wscv,
    int layer, int N)
{
  int t = blockIdx.x * 256 + threadIdx.x;
  int n = t / 80; int slot = t - n * 80;
  if (n >= N) return;
  if (slot < 32) {
    const float* W = wscs + layer * 1024;
    float acc = 0.f;
    #pragma unroll
    for (int u = 0; u < 32; ++u) acc += sc[n * 32 + u] * W[u * 32 + slot];
    sn[n * 32 + slot] = acc * INV_SQRT_S_F;
  } else {
    int j = slot - 32; int w = j / 3; int k = j - w * 3;
    const float* W = wscv + layer * 256;
    float acc = 0.f;
    #pragma unroll
    for (int u = 0; u < 16; ++u) acc += vc[n * 48 + u * 3 + k] * W[u * 16 + w];
    vn[n * 48 + j] = acc * INV_SQRT_V_F;
  }
}

// ---------------- edge kernel: MFMA h-first ----------------
// Block = 64 edges, 4 waves. Wave q's M-tile = edges [16q,16q+16).
// Per (u, j-chunk) tile: one compensated-bf16 MFMA computes Wh[e][j-chunk]
// (j = u*32+w for W1 etc.); consumption folds sj/vd/vj (read as per-quad
// float4 from LDS) into per-lane accumulators already in C-layout
// (col = w, row-reg = edge). Messages -> sX -> round-7 pg/gate/Wlo phase.
__global__ __launch_bounds__(256, 3) void edge_kernel(
    const int* __restrict__ ei, const float* __restrict__ ed,
    const float* __restrict__ esh,
    const float* __restrict__ sc, const float* __restrict__ vc,
    float* __restrict__ sn, float* __restrict__ vn,
    const float* __restrict__ wr1, const float* __restrict__ br1,
    const unsigned short* __restrict__ wfh, const unsigned short* __restrict__ wfl,
    const float* __restrict__ br2,
    const float* __restrict__ wpgs, const float* __restrict__ wpgv,
    const float* __restrict__ wlos, const float* __restrict__ wlov,
    int layer, int E, int N)
{
  __shared__ __align__(16) float sX[64 * 81];   // messages/gates; front aliases sH
  __shared__ __align__(16) float sSj[32 * 64];  // [u][e]
  __shared__ __align__(16) float sVd[16 * 64];  // [u][e]
  __shared__ __align__(16) float sVj[48 * 64];  // [u*3+k][e]
  __shared__ __align__(16) float sY[4 * 64];    // [comp][e]
  float* const sH = sX;                         // [e][32] stride 33, dead after frags

  const int tid  = threadIdx.x;
  const int lane = tid & 63;
  const int q    = tid >> 6;
  const int col  = lane & 15;
  const int quad = lane >> 4;
  const int wq8  = q * 8;
  const int wq4  = q * 4;
  const int e    = blockIdx.x * 64 + lane;
  const bool valid = e < E;
  const int eL   = valid ? e : (E - 1);
  int srcn = ei[eL];     srcn = (srcn < 0) ? 0 : (srcn >= N ? N - 1 : srcn);
  int dstn = ei[E + eL]; dstn = (dstn < 0) ? 0 : (dstn >= N ? N - 1 : dstn);
  const float y0  = esh[eL * 4 + 0];
  const float y1x = esh[eL * 4 + 1];
  const float y1y = esh[eL * 4 + 2];
  const float y1z = esh[eL * 4 + 3];

  // ---- stage: h (wave-split over j), sSj/sVd/sVj (wave-split over u), sY ----
  {
    const float d = ed[eL];
    const float inv_w = 12.0f / CUTOFF_F;
    float cut = (d < CUTOFF_F) ? 0.5f * (__cosf(d * (PI_F / CUTOFF_F)) + 1.0f) : 0.0f;
    float rb[6];
    #pragma unroll
    for (int r = 0; r < 6; ++r) {
      float z = (d - 0.07f * (float)r) * inv_w;
      rb[r] = __expf(-0.5f * z * z) * cut;
    }
    const float* W1p = wr1 + layer * 192;
    const float* B1p = br1 + layer * 32;
    #pragma unroll
    for (int jj = 0; jj < 8; ++jj) {
      const int j = wq8 + jj;
      float z = B1p[j];
      #pragma unroll
      for (int r = 0; r < 6; ++r) z += rb[r] * W1p[r * 32 + j];
      sH[lane * 33 + j] = z / (1.0f + __expf(-z));   // silu
    }
  }
  { // sSj: wave q stages u in [8q, 8q+8)
    const f32x4* sp = (const f32x4*)(sc + (size_t)srcn * 32 + wq8);
    f32x4 a = sp[0], b = sp[1];
    #pragma unroll
    for (int i = 0; i < 4; ++i) {
      sSj[(wq8 + i) * 64 + lane]     = a[i];
      sSj[(wq8 + 4 + i) * 64 + lane] = b[i];
    }
  }
  { // sVj + sVd: wave q stages u in [4q, 4q+4)
    const f32x4* vp = (const f32x4*)(vc + (size_t)srcn * 48 + wq4 * 3);
    f32x4 a = vp[0], b = vp[1], c = vp[2];
    float vtmp[12];
    #pragma unroll
    for (int i = 0; i < 4; ++i) { vtmp[i] = a[i]; vtmp[4+i] = b[i]; vtmp[8+i] = c[i]; }
    #pragma unroll
    for (int i = 0; i < 12; ++i) sVj[(wq4 * 3 + i) * 64 + lane] = vtmp[i];
    #pragma unroll
    for (int u = 0; u < 4; ++u)
      sVd[(wq4 + u) * 64 + lane] =
          vtmp[u*3] * y1x + vtmp[u*3+1] * y1y + vtmp[u*3+2] * y1z;
  }
  if (q == 0) {
    sY[0 * 64 + lane] = y0;  sY[1 * 64 + lane] = y1x;
    sY[2 * 64 + lane] = y1y; sY[3 * 64 + lane] = y1z;
  }
  __syncthreads();   // B1: staging done

  // ---- A-fragments (compensated): m = col (edge in M-tile), k = quad*8+i ----
  bshort8 ahi, alo;
  #pragma unroll
  for (int i = 0; i < 8; ++i) {
    float hv = sH[(q * 16 + col) * 33 + (quad * 8 + i)];
    unsigned short h = f2b(hv);
    ahi[i] = (short)h;
    alo[i] = (short)f2b(hv - b2f(h));
  }
  __syncthreads();   // B2: sH dead, sX writable

  const bshort8* wbh = (const bshort8*)wfh + (size_t)layer * 144 * 64 + lane;
  const bshort8* wbl = (const bshort8*)wfl + (size_t)layer * 144 * 64 + lane;
  const float* br2L = br2 + (size_t)layer * 2304;
  const int eb = q * 16 + quad * 4;    // base block-local edge for the 4 C-regs

  const f32x4 y0v  = *(const f32x4*)&sY[0 * 64 + eb];
  const f32x4 y1xv = *(const f32x4*)&sY[1 * 64 + eb];
  const f32x4 y1yv = *(const f32x4*)&sY[2 * 64 + eb];
  const f32x4 y1zv = *(const f32x4*)&sY[3 * 64 + eb];

  float accA[8], accB[8], accC[4], accD[12];
  #pragma unroll
  for (int i = 0; i < 8; ++i) { accA[i] = 0.f; accB[i] = 0.f; }
  #pragma unroll
  for (int i = 0; i < 4; ++i) accC[i] = 0.f;
  #pragma unroll
  for (int i = 0; i < 12; ++i) accD[i] = 0.f;

  // ---- W1 (tiles 2u, 2u+1) and W3 (tile 96+u), left = sj ----
  for (int u = 0; u < 32; ++u) {
    const f32x4 sj4 = *(const f32x4*)&sSj[u * 64 + eb];
    #pragma unroll
    for (int ch = 0; ch < 2; ++ch) {
      const int t = u * 2 + ch;
      f32x4 cc = mfma3(ahi, alo, wbh[(size_t)t * 64], wbl[(size_t)t * 64]);
      const float bb = br2L[t * 16 + col];
      #pragma unroll
      for (int r = 0; r < 4; ++r) accA[ch * 4 + r] += sj4[r] * (cc[r] + bb);
    }
    {
      const int t = 96 + u;
      f32x4 cc = mfma3(ahi, alo, wbh[(size_t)t * 64], wbl[(size_t)t * 64]);
      const float bb = br2L[t * 16 + col];
      #pragma unroll
      for (int r = 0; r < 4; ++r) accC[r] += sj4[r] * (cc[r] + bb);
    }
  }
  // ---- W2 (tiles 64+2u, +1) left = vdot; W4 (tile 128+u) left = vj[k] ----
  for (int u = 0; u < 16; ++u) {
    const f32x4 vd4 = *(const f32x4*)&sVd[u * 64 + eb];
    #pragma unroll
    for (int ch = 0; ch < 2; ++ch) {
      const int t = 64 + u * 2 + ch;
      f32x4 cc = mfma3(ahi, alo, wbh[(size_t)t * 64], wbl[(size_t)t * 64]);
      const float bb = br2L[t * 16 + col];
      #pragma unroll
      for (int r = 0; r < 4; ++r) accB[ch * 4 + r] += vd4[r] * (cc[r] + bb);
    }
    {
      const int t = 128 + u;
      f32x4 cc = mfma3(ahi, alo, wbh[(size_t)t * 64], wbl[(size_t)t * 64]);
      const float bb = br2L[t * 16 + col];
      #pragma unroll
      for (int k = 0; k < 3; ++k) {
        const f32x4 vj4 = *(const f32x4*)&sVj[(u * 3 + k) * 64 + eb];
        #pragma unroll
        for (int r = 0; r < 4; ++r) accD[k * 4 + r] += vj4[r] * (cc[r] + bb);
      }
    }
  }

  // ---- messages into sX (transpose C-layout -> per-edge rows) ----
  #pragma unroll
  for (int ch = 0; ch < 2; ++ch)
    #pragma unroll
    for (int r = 0; r < 4; ++r)
      sX[(eb + r) * 81 + ch * 16 + col] =
          A_SC_F * (y0v[r] * accA[ch * 4 + r] + INV_SQRT3_F * accB[ch * 4 + r]);
  #pragma unroll
  for (int r = 0; r < 4; ++r) {
    sX[(eb + r) * 81 + 32 + col * 3 + 0] = A_SC_F * (accC[r] * y1xv[r] + y0v[r] * accD[0 + r]);
    sX[(eb + r) * 81 + 32 + col * 3 + 1] = A_SC_F * (accC[r] * y1yv[r] + y0v[r] * accD[4 + r]);
    sX[(eb + r) * 81 + 32 + col * 3 + 2] = A_SC_F * (accC[r] * y1zv[r] + y0v[r] * accD[8 + r]);
  }
  __syncthreads();   // B3: full ms/mv visible

  // ---- pg phase (round-7 validated choreography, stride 81) ----
  float ps[8], pt[4];
  #pragma unroll
  for (int i = 0; i < 8; ++i) ps[i] = 0.f;
  #pragma unroll
  for (int i = 0; i < 4; ++i) pt[i] = 0.f;
  {
    const float* Wp = wpgs + layer * 1536;
    #pragma unroll
    for (int u = 0; u < 32; ++u) {
      const float ms = sX[lane * 81 + u];
      #pragma unroll
      for (int jj = 0; jj < 8; ++jj) ps[jj] += ms * Wp[u * 48 + wq8 + jj];
      #pragma unroll
      for (int wi = 0; wi < 4; ++wi) pt[wi] += ms * Wp[u * 48 + 32 + wq4 + wi];
    }
  }
  float pv[12];
  #pragma unroll
  for (int i = 0; i < 12; ++i) pv[i] = 0.f;
  {
    const float* Wp = wpgv + layer * 256;
    #pragma unroll
    for (int u = 0; u < 16; ++u) {
      const float m0 = sX[lane * 81 + 32 + u * 3 + 0];
      const float m1 = sX[lane * 81 + 32 + u * 3 + 1];
      const float m2 = sX[lane * 81 + 32 + u * 3 + 2];
      #pragma unroll
      for (int wi = 0; wi < 4; ++wi) {
        const float wv = Wp[u * 16 + wq4 + wi];
        pv[wi * 3 + 0] += m0 * wv;
        pv[wi * 3 + 1] += m1 * wv;
        pv[wi * 3 + 2] += m2 * wv;
      }
    }
  }
  __syncthreads();   // B4: pg reads done

  #pragma unroll
  for (int jj = 0; jj < 8; ++jj) {
    const float t = ps[jj] * INV_SQRT_S_F;
    sX[lane * 81 + wq8 + jj] = t / (1.0f + __expf(-t));            // silu
  }
  #pragma unroll
  for (int wi = 0; wi < 4; ++wi) {
    const float g = 1.0f / (1.0f + __expf(-pt[wi] * INV_SQRT_S_F)); // sigmoid
    #pragma unroll
    for (int k = 0; k < 3; ++k)
      sX[lane * 81 + 32 + (wq4 + wi) * 3 + k] = g * pv[wi * 3 + k] * INV_SQRT_V_F;
  }
  __syncthreads();   // B5: gates visible

  float os[8];
  #pragma unroll
  for (int i = 0; i < 8; ++i) os[i] = 0.f;
  {
    const float* Wp = wlos + layer * 1024;
    #pragma unroll
    for (int u = 0; u < 32; ++u) {
      const float g = sX[lane * 81 + u];
      #pragma unroll
      for (int wi = 0; wi < 8; ++wi) os[wi] += g * Wp[u * 32 + wq8 + wi];
    }
  }
  float ov[12];
  #pragma unroll
  for (int i = 0; i < 12; ++i) ov[i] = 0.f;
  {
    const float* Wp = wlov + layer * 256;
    #pragma unroll
    for (int u = 0; u < 16; ++u) {
      const float g0 = sX[lane * 81 + 32 + u * 3 + 0];
      const float g1 = sX[lane * 81 + 32 + u * 3 + 1];
      const float g2 = sX[lane * 81 + 32 + u * 3 + 2];
      #pragma unroll
      for (int wi = 0; wi < 4; ++wi) {
        const float wv = Wp[u * 16 + wq4 + wi];
        ov[wi * 3 + 0] += g0 * wv;
        ov[wi * 3 + 1] += g1 * wv;
        ov[wi * 3 + 2] += g2 * wv;
      }
    }
  }
  if (valid) {
    float* sd = sn + (size_t)dstn * 32 + wq8;
    #pragma unroll
    for (int wi = 0; wi < 8; ++wi) unsafeAtomicAdd(&sd[wi], os[wi] * INV_SQRT_S_F);
    float* vd = vn + (size_t)dstn * 48 + wq4 * 3;
    #pragma unroll
    for (int j = 0; j < 12; ++j) unsafeAtomicAdd(&vd[j], ov[j] * INV_SQRT_V_F);
  }
}

// out[n,k] = coeffs[n] @ M  — FP32 OUTPUT
__global__ __launch_bounds__(256) void final_kernel(
    const float* __restrict__ s0, const float* __restrict__ v0,
    const float* __restrict__ wos, const float* __restrict__ wov,
    const float* __restrict__ wf, float* __restrict__ out, int N)
{
  int n = blockIdx.x * 256 + threadIdx.x;
  if (n >= N) return;
  float cs = 0.f;
  #pragma unroll
  for (int u = 0; u < 32; ++u) cs += s0[n * 32 + u] * wos[u];
  cs *= INV_SQRT_S_F;
  float cv0 = 0.f, cv1 = 0.f, cv2 = 0.f;
  #pragma unroll
  for (int u = 0; u < 16; ++u) {
    const float wv = wov[u];
    cv0 += v0[n * 48 + u * 3 + 0] * wv;
    cv1 += v0[n * 48 + u * 3 + 1] * wv;
    cv2 += v0[n * 48 + u * 3 + 2] * wv;
  }
  cv0 *= INV_SQRT_V_F; cv1 *= INV_SQRT_V_F; cv2 *= INV_SQRT_V_F;
  #pragma unroll
  for (int k = 0; k < 3; ++k) {
    out[n * 3 + k] = cs  * wf[OFF_M + k]
                   + cv0 * wf[OFF_M + 3 + k]
                   + cv1 * wf[OFF_M + 6 + k]
                   + cv2 * wf[OFF_M + 9 + k];
  }
}

extern "C" void kernel_launch(void* const* d_in, const int* in_sizes, int n_in,
                              void* d_out, int out_size, void* d_ws, size_t ws_size,
                              hipStream_t stream)
{
  (void)n_in; (void)out_size; (void)ws_size;
  const float* x    = (const float*)d_in[0];
  const int*   ei   = (const int*)d_in[1];
  const float* ed   = (const float*)d_in[2];
  const float* esh  = (const float*)d_in[3];
  const float* dirs = (const float*)d_in[4];
  const float* wins = (const float*)d_in[5];
  const float* winv = (const float*)d_in[6];
  const float* wscs = (const float*)d_in[7];
  const float* wscv = (const float*)d_in[8];
  const float* wr1  = (const float*)d_in[9];
  const float* br1  = (const float*)d_in[10];
  const float* wr2  = (const float*)d_in[11];
  const float* br2  = (const float*)d_in[12];
  const float* wpgs = (const float*)d_in[13];
  const float* wpgv = (const float*)d_in[14];
  const float* wlos = (const float*)d_in[15];
  const float* wlov = (const float*)d_in[16];
  const float* wos  = (const float*)d_in[17];
  const float* wov  = (const float*)d_in[18];

  const int N = in_sizes[0] / 6;
  const int E = in_sizes[1] / 2;

  float* wf = (float*)d_ws;
  unsigned short* fhi = (unsigned short*)(wf + OFF_FRAGHI);
  unsigned short* flo = (unsigned short*)(wf + OFF_FRAGLO);
  float* s0 = wf + OFF_NODE;
  float* v0 = s0 + (size_t)N * 32;
  float* s1 = v0 + (size_t)N * 48;
  float* v1 = s1 + (size_t)N * 32;

  const int nodeBlocks = (N * 80 + 255) / 256;
  const int edgeBlocks = (E + 63) / 64;
  const int finBlocks  = (N + 255) / 256;

  fragpack_kernel<<<(147456 + 255) / 256, 256, 0, stream>>>(wr2, fhi, flo);
  mmat_kernel<<<1, 64, 0, stream>>>(dirs, wf);
  node_init_kernel<<<nodeBlocks, 256, 0, stream>>>(x, wins, winv, s0, v0, N);

  // layer 0: s0/v0 -> s1/v1
  selfmix_kernel<<<nodeBlocks, 256, 0, stream>>>(s0, v0, s1, v1, wscs, wscv, 0, N);
  edge_kernel<<<edgeBlocks, 256, 0, stream>>>(ei, ed, esh, s0, v0, s1, v1,
      wr1, br1, fhi, flo, br2, wpgs, wpgv, wlos, wlov, 0, E, N);
  // layer 1: s1/v1 -> s0/v0
  selfmix_kernel<<<nodeBlocks, 256, 0, stream>>>(s1, v1, s0, v0, wscs, wscv, 1, N);
  edge_kernel<<<edgeBlocks, 256, 0, stream>>>(ei, ed, esh, s1, v1, s0, v0,
      wr1, br1, fhi, flo, br2, wpgs, wpgv, wlos, wlov, 1, E, N);

  final_kernel<<<finBlocks, 256, 0, stream>>>(s0, v0, wos, wov, wf,
      (float*)d_out, N);
}

// Round 10
// 709.015 us; speedup vs baseline: 1.3268x; 1.1205x over previous
//
#include <hip/hip_runtime.h>

// ---------------- constants ----------------
#define CUTOFF_F     0.35f
#define PI_F         3.14159265358979323846f
#define SQRT3_F      1.7320508075688772f
#define INV_SQRT3_F  0.5773502691896258f
#define INV_SQRT_S_F 0.17677669529663687f   // 1/sqrt(32)
#define INV_SQRT_V_F 0.25f                  // 1/sqrt(16)
#define A_SC_F       0.14433756729740643f   // 1/sqrt(48)

// ws layout (floats): [0..12) M | fragHi | fragLo | node buffers
#define OFF_M      0
#define OFF_FRAGHI 16        // 147456 ushort = 73728 floats
#define OFF_FRAGLO 73744
#define OFF_NODE   147472

// LDS union (floats)
#define SH_H    0                 // 128*33 = 4224 (hext, stride 33)
#define SH_SJ   4224              // 32*128 = 4096
#define SH_VD   (4224+4096)       // 16*128 = 2048
#define SH_VJ   (4224+6144)       // 48*128 = 6144
#define SH_X    4224              // 128*81 = 10368 (aliases SJ/VD/VJ after B3)
#define SH_Y    (4224+12288)      // 4*128 = 512
#define SH_TOT  (4224+12288+512)  // 17024 floats = 68096 B -> 2 blocks/CU

typedef __attribute__((ext_vector_type(8))) short bshort8;
typedef __attribute__((ext_vector_type(4))) float f32x4;

static __device__ __forceinline__ float b2f(unsigned short u) {
  union { unsigned int i; float f; } x; x.i = ((unsigned int)u) << 16; return x.f;
}
static __device__ __forceinline__ unsigned short f2b(float f) {
  union { float f; unsigned int i; } x; x.f = f;
  unsigned int i = x.i;
  return (unsigned short)((i + 0x7FFFu + ((i >> 16) & 1u)) >> 16);
}
// compensated bf16 product: 2-MFMA chain (residual terms) + 1 independent MFMA
static __device__ __forceinline__ f32x4 mfma_c(bshort8 ah, bshort8 al, bshort8 bh, bshort8 bl) {
  f32x4 z = {0.f, 0.f, 0.f, 0.f};
  z = __builtin_amdgcn_mfma_f32_16x16x32_bf16(al, bh, z, 0, 0, 0);
  z = __builtin_amdgcn_mfma_f32_16x16x32_bf16(ah, bl, z, 0, 0, 0);
  f32x4 m = {0.f, 0.f, 0.f, 0.f};
  m = __builtin_amdgcn_mfma_f32_16x16x32_bf16(ah, bh, m, 0, 0, 0);
  return z + m;
}

// pack Wr2 into MFMA B-fragments, compensated bf16 (hi + lo residual)
// frag idx = ((layer*144 + t)*64 + lane)*8 + i ; B[k=quad*8+i][col] = W[c][j]
__global__ __launch_bounds__(256) void fragpack_kernel(
    const float* __restrict__ wr2, unsigned short* __restrict__ fhi,
    unsigned short* __restrict__ flo)
{
  int idx = blockIdx.x * 256 + threadIdx.x;
  if (idx >= 147456) return;
  int i    = idx & 7;
  int lane = (idx >> 3) & 63;
  int tl   = idx >> 9;
  int t    = tl % 144;
  int layer = tl / 144;
  int c = (lane >> 4) * 8 + i;
  int j = t * 16 + (lane & 15);
  float w = wr2[((size_t)(layer * 32 + c)) * 2304 + j];
  unsigned short h = f2b(w);
  fhi[idx] = h;
  flo[idx] = f2b(w - b2f(h));
}

// M[c][k] = (1/256) * Y[:,c] . dirs[:,k]
__global__ void mmat_kernel(const float* __restrict__ dirs, float* __restrict__ wf) {
  int t = threadIdx.x;
  if (t >= 12) return;
  int c = t / 3, k = t - c * 3;
  float acc = 0.f;
  for (int p = 0; p < 256; ++p) {
    float dk = dirs[p * 3 + k];
    acc += (c == 0) ? dk : dirs[p * 3 + (c - 1)] * dk;
  }
  wf[OFF_M + t] = acc * ((c == 0) ? (1.0f / 256.0f) : (SQRT3_F / 256.0f));
}

__global__ __launch_bounds__(256) void node_init_kernel(
    const float* __restrict__ x, const float* __restrict__ wins,
    const float* __restrict__ winv,
    float* __restrict__ s0, float* __restrict__ v0, int N)
{
  int t = blockIdx.x * 256 + threadIdx.x;
  int n = t / 80; int slot = t - n * 80;
  if (n >= N) return;
  if (slot < 32) {
    float acc = 0.f;
    #pragma unroll
    for (int d = 0; d < 3; ++d) acc += x[n * 6 + d] * wins[d * 32 + slot];
    s0[n * 32 + slot] = acc * INV_SQRT3_F;
  } else {
    int j = slot - 32; int u = j / 3; int k = j - u * 3;
    v0[n * 48 + j] = x[n * 6 + 3 + k] * winv[u];
  }
}

__global__ __launch_bounds__(256) void selfmix_kernel(
    const float* __restrict__ sc, const float* __restrict__ vc,
    float* __restrict__ sn, float* __restrict__ vn,
    const float* __restrict__ wscs, const float* __restrict__ wscv,
    int layer, int N)
{
  int t = blockIdx.x * 256 + threadIdx.x;
  int n = t / 80; int slot = t - n * 80;
  if (n >= N) return;
  if (slot < 32) {
    const float* W = wscs + layer * 1024;
    float acc = 0.f;
    #pragma unroll
    for (int u = 0; u < 32; ++u) acc += sc[n * 32 + u] * W[u * 32 + slot];
    sn[n * 32 + slot] = acc * INV_SQRT_S_F;
  } else {
    int j = slot - 32; int w = j / 3; int k = j - w * 3;
    const float* W = wscv + layer * 256;
    float acc = 0.f;
    #pragma unroll
    for (int u = 0; u < 16; ++u) acc += vc[n * 48 + u * 3 + k] * W[u * 16 + w];
    vn[n * 48 + j] = acc * INV_SQRT_V_F;
  }
}

// ---------------- edge kernel: MFMA h-first, 128 edges/block, 2 M-tiles/wave --
__global__ __launch_bounds__(256, 2) void edge_kernel(
    const int* __restrict__ ei, const float* __restrict__ ed,
    const float* __restrict__ esh,
    const float* __restrict__ sc, const float* __restrict__ vc,
    float* __restrict__ sn, float* __restrict__ vn,
    const float* __restrict__ wr1, const float* __restrict__ br1,
    const unsigned short* __restrict__ wfh, const unsigned short* __restrict__ wfl,
    const float* __restrict__ br2,
    const float* __restrict__ wpgs, const float* __restrict__ wpgv,
    const float* __restrict__ wlos, const float* __restrict__ wlov,
    int layer, int E, int N)
{
  __shared__ __align__(16) float sm[SH_TOT];

  const int tid  = threadIdx.x;
  const int lane = tid & 63;
  const int q    = tid >> 6;
  const int col  = lane & 15;
  const int quad = lane >> 4;
  const int wq8  = q * 8;
  const int wq4  = q * 4;
  const int ge0  = blockIdx.x * 128 + lane;     // edge A (block-local = lane)
  const int ge1  = ge0 + 64;                    // edge B (block-local = lane+64)
  const bool ok0 = ge0 < E, ok1 = ge1 < E;
  const int eL0  = ok0 ? ge0 : E - 1;
  const int eL1  = ok1 ? ge1 : E - 1;
  int sn0 = ei[eL0];     sn0 = (sn0 < 0) ? 0 : (sn0 >= N ? N - 1 : sn0);
  int sn1 = ei[eL1];     sn1 = (sn1 < 0) ? 0 : (sn1 >= N ? N - 1 : sn1);
  int dn0 = ei[E + eL0]; dn0 = (dn0 < 0) ? 0 : (dn0 >= N ? N - 1 : dn0);
  int dn1 = ei[E + eL1]; dn1 = (dn1 < 0) ? 0 : (dn1 >= N ? N - 1 : dn1);
  const float y00 = esh[eL0*4+0], y0x = esh[eL0*4+1], y0y = esh[eL0*4+2], y0z = esh[eL0*4+3];
  const float y10 = esh[eL1*4+0], y1x = esh[eL1*4+1], y1y = esh[eL1*4+2], y1z = esh[eL1*4+3];

  // ---- stage h (wave-split over j, 2 edges/lane) ----
  {
    const float d0 = ed[eL0], d1 = ed[eL1];
    const float inv_w = 12.0f / CUTOFF_F;
    float cut0 = (d0 < CUTOFF_F) ? 0.5f * (__cosf(d0 * (PI_F / CUTOFF_F)) + 1.0f) : 0.0f;
    float cut1 = (d1 < CUTOFF_F) ? 0.5f * (__cosf(d1 * (PI_F / CUTOFF_F)) + 1.0f) : 0.0f;
    float rb0[6], rb1[6];
    #pragma unroll
    for (int r = 0; r < 6; ++r) {
      float z0 = (d0 - 0.07f * (float)r) * inv_w;
      float z1 = (d1 - 0.07f * (float)r) * inv_w;
      rb0[r] = __expf(-0.5f * z0 * z0) * cut0;
      rb1[r] = __expf(-0.5f * z1 * z1) * cut1;
    }
    const float* W1p = wr1 + layer * 192;
    const float* B1p = br1 + layer * 32;
    #pragma unroll
    for (int jj = 0; jj < 8; ++jj) {
      const int j = wq8 + jj;
      float z0 = B1p[j], z1 = z0;
      #pragma unroll
      for (int r = 0; r < 6; ++r) {
        const float wv = W1p[r * 32 + j];
        z0 += rb0[r] * wv; z1 += rb1[r] * wv;
      }
      sm[SH_H + lane * 33 + j]        = z0 / (1.0f + __expf(-z0));
      sm[SH_H + (lane + 64) * 33 + j] = z1 / (1.0f + __expf(-z1));
    }
  }
  // ---- stage sSj (wave-split over u, 2 edges/lane) ----
  {
    const f32x4* p0 = (const f32x4*)(sc + (size_t)sn0 * 32 + wq8);
    f32x4 a = p0[0], b = p0[1];
    #pragma unroll
    for (int i = 0; i < 4; ++i) {
      sm[SH_SJ + (wq8 + i) * 128 + lane]     = a[i];
      sm[SH_SJ + (wq8 + 4 + i) * 128 + lane] = b[i];
    }
    const f32x4* p1 = (const f32x4*)(sc + (size_t)sn1 * 32 + wq8);
    a = p1[0]; b = p1[1];
    #pragma unroll
    for (int i = 0; i < 4; ++i) {
      sm[SH_SJ + (wq8 + i) * 128 + lane + 64]     = a[i];
      sm[SH_SJ + (wq8 + 4 + i) * 128 + lane + 64] = b[i];
    }
  }
  // ---- stage sVj + sVd ----
  {
    const f32x4* vp = (const f32x4*)(vc + (size_t)sn0 * 48 + wq4 * 3);
    f32x4 a = vp[0], b = vp[1], c = vp[2];
    float vt[12];
    #pragma unroll
    for (int i = 0; i < 4; ++i) { vt[i] = a[i]; vt[4+i] = b[i]; vt[8+i] = c[i]; }
    #pragma unroll
    for (int i = 0; i < 12; ++i) sm[SH_VJ + (wq4 * 3 + i) * 128 + lane] = vt[i];
    #pragma unroll
    for (int u = 0; u < 4; ++u)
      sm[SH_VD + (wq4 + u) * 128 + lane] =
          vt[u*3] * y0x + vt[u*3+1] * y0y + vt[u*3+2] * y0z;
    vp = (const f32x4*)(vc + (size_t)sn1 * 48 + wq4 * 3);
    a = vp[0]; b = vp[1]; c = vp[2];
    #pragma unroll
    for (int i = 0; i < 4; ++i) { vt[i] = a[i]; vt[4+i] = b[i]; vt[8+i] = c[i]; }
    #pragma unroll
    for (int i = 0; i < 12; ++i) sm[SH_VJ + (wq4 * 3 + i) * 128 + lane + 64] = vt[i];
    #pragma unroll
    for (int u = 0; u < 4; ++u)
      sm[SH_VD + (wq4 + u) * 128 + lane + 64] =
          vt[u*3] * y1x + vt[u*3+1] * y1y + vt[u*3+2] * y1z;
  }
  if (q == 0) {
    sm[SH_Y + 0*128 + lane] = y00;  sm[SH_Y + 1*128 + lane] = y0x;
    sm[SH_Y + 2*128 + lane] = y0y;  sm[SH_Y + 3*128 + lane] = y0z;
    sm[SH_Y + 0*128 + lane + 64] = y10;  sm[SH_Y + 1*128 + lane + 64] = y1x;
    sm[SH_Y + 2*128 + lane + 64] = y1y;  sm[SH_Y + 3*128 + lane + 64] = y1z;
  }
  __syncthreads();   // B1: staging done

  // ---- A-fragments for this wave's 2 M-tiles (edges [32q+16mt, +16)) ----
  bshort8 a0h, a0l, a1h, a1l;
  #pragma unroll
  for (int i = 0; i < 8; ++i) {
    float h0 = sm[SH_H + (32*q + col) * 33 + quad * 8 + i];
    float h1 = sm[SH_H + (32*q + 16 + col) * 33 + quad * 8 + i];
    unsigned short hh0 = f2b(h0), hh1 = f2b(h1);
    a0h[i] = (short)hh0; a0l[i] = (short)f2b(h0 - b2f(hh0));
    a1h[i] = (short)hh1; a1l[i] = (short)f2b(h1 - b2f(hh1));
  }

  const bshort8* wbh = (const bshort8*)wfh + (size_t)layer * 144 * 64 + lane;
  const bshort8* wbl = (const bshort8*)wfl + (size_t)layer * 144 * 64 + lane;
  const float* br2L = br2 + (size_t)layer * 2304;
  const int eb0 = 32*q + quad * 4;   // C-reg base edge, M-tile 0
  const int eb1 = eb0 + 16;          // M-tile 1

  float accA0[8], accA1[8], accB0[8], accB1[8];
  float accC0[4], accC1[4], accD0[12], accD1[12];
  #pragma unroll
  for (int i = 0; i < 8; ++i) { accA0[i]=0.f; accA1[i]=0.f; accB0[i]=0.f; accB1[i]=0.f; }
  #pragma unroll
  for (int i = 0; i < 4; ++i) { accC0[i]=0.f; accC1[i]=0.f; }
  #pragma unroll
  for (int i = 0; i < 12; ++i) { accD0[i]=0.f; accD1[i]=0.f; }

  // ---- W1/W3 loop: tiles 2u, 2u+1, 96+u; prefetch next iteration ----
  {
    bshort8 h0 = wbh[0*64],  l0 = wbl[0*64];
    bshort8 h1 = wbh[1*64],  l1 = wbl[1*64];
    bshort8 h2 = wbh[96*64], l2 = wbl[96*64];
    for (int u = 0; u < 32; ++u) {
      const bshort8 c0h=h0, c0l=l0, c1h=h1, c1l=l1, c2h=h2, c2l=l2;
      if (u < 31) {
        h0 = wbh[(size_t)(2*u+2)*64];  l0 = wbl[(size_t)(2*u+2)*64];
        h1 = wbh[(size_t)(2*u+3)*64];  l1 = wbl[(size_t)(2*u+3)*64];
        h2 = wbh[(size_t)(97+u)*64];   l2 = wbl[(size_t)(97+u)*64];
      }
      const float bb0 = br2L[(2*u)*16 + col];
      const float bb1 = br2L[(2*u+1)*16 + col];
      const float bb2 = br2L[(96+u)*16 + col];
      const f32x4 sj0 = *(const f32x4*)&sm[SH_SJ + u*128 + eb0];
      const f32x4 sj1 = *(const f32x4*)&sm[SH_SJ + u*128 + eb1];
      f32x4 t00 = mfma_c(a0h, a0l, c0h, c0l);
      f32x4 t01 = mfma_c(a1h, a1l, c0h, c0l);
      f32x4 t10 = mfma_c(a0h, a0l, c1h, c1l);
      f32x4 t11 = mfma_c(a1h, a1l, c1h, c1l);
      f32x4 t20 = mfma_c(a0h, a0l, c2h, c2l);
      f32x4 t21 = mfma_c(a1h, a1l, c2h, c2l);
      #pragma unroll
      for (int r = 0; r < 4; ++r) {
        accA0[r]   += sj0[r] * (t00[r] + bb0);
        accA1[r]   += sj1[r] * (t01[r] + bb0);
        accA0[4+r] += sj0[r] * (t10[r] + bb1);
        accA1[4+r] += sj1[r] * (t11[r] + bb1);
        accC0[r]   += sj0[r] * (t20[r] + bb2);
        accC1[r]   += sj1[r] * (t21[r] + bb2);
      }
    }
  }
  // ---- W2/W4 loop: tiles 64+2u, 65+2u, 128+u ----
  {
    bshort8 h0 = wbh[64*64],  l0 = wbl[64*64];
    bshort8 h1 = wbh[65*64],  l1 = wbl[65*64];
    bshort8 h2 = wbh[128*64], l2 = wbl[128*64];
    for (int u = 0; u < 16; ++u) {
      const bshort8 c0h=h0, c0l=l0, c1h=h1, c1l=l1, c2h=h2, c2l=l2;
      if (u < 15) {
        h0 = wbh[(size_t)(66+2*u)*64];  l0 = wbl[(size_t)(66+2*u)*64];
        h1 = wbh[(size_t)(67+2*u)*64];  l1 = wbl[(size_t)(67+2*u)*64];
        h2 = wbh[(size_t)(129+u)*64];   l2 = wbl[(size_t)(129+u)*64];
      }
      const float bb0 = br2L[(64+2*u)*16 + col];
      const float bb1 = br2L[(65+2*u)*16 + col];
      const float bb2 = br2L[(128+u)*16 + col];
      const f32x4 vd0 = *(const f32x4*)&sm[SH_VD + u*128 + eb0];
      const f32x4 vd1 = *(const f32x4*)&sm[SH_VD + u*128 + eb1];
      f32x4 t00 = mfma_c(a0h, a0l, c0h, c0l);
      f32x4 t01 = mfma_c(a1h, a1l, c0h, c0l);
      f32x4 t10 = mfma_c(a0h, a0l, c1h, c1l);
      f32x4 t11 = mfma_c(a1h, a1l, c1h, c1l);
      f32x4 t20 = mfma_c(a0h, a0l, c2h, c2l);
      f32x4 t21 = mfma_c(a1h, a1l, c2h, c2l);
      #pragma unroll
      for (int r = 0; r < 4; ++r) {
        accB0[r]   += vd0[r] * (t00[r] + bb0);
        accB1[r]   += vd1[r] * (t01[r] + bb0);
        accB0[4+r] += vd0[r] * (t10[r] + bb1);
        accB1[4+r] += vd1[r] * (t11[r] + bb1);
      }
      #pragma unroll
      for (int k = 0; k < 3; ++k) {
        const f32x4 vj0 = *(const f32x4*)&sm[SH_VJ + (u*3+k)*128 + eb0];
        const f32x4 vj1 = *(const f32x4*)&sm[SH_VJ + (u*3+k)*128 + eb1];
        #pragma unroll
        for (int r = 0; r < 4; ++r) {
          accD0[k*4+r] += vj0[r] * (t20[r] + bb2);
          accD1[k*4+r] += vj1[r] * (t21[r] + bb2);
        }
      }
    }
  }
  __syncthreads();   // B3: all waves done reading SJ/VD/VJ -> sX may overwrite

  // ---- messages into sX (per M-tile; y via sY which is NOT aliased) ----
  #pragma unroll
  for (int mt = 0; mt < 2; ++mt) {
    const int ebm = (mt == 0) ? eb0 : eb1;
    const float* aA = (mt == 0) ? accA0 : accA1;
    const float* aB = (mt == 0) ? accB0 : accB1;
    const float* aC = (mt == 0) ? accC0 : accC1;
    const float* aD = (mt == 0) ? accD0 : accD1;
    const f32x4 y0v  = *(const f32x4*)&sm[SH_Y + 0*128 + ebm];
    const f32x4 y1xv = *(const f32x4*)&sm[SH_Y + 1*128 + ebm];
    const f32x4 y1yv = *(const f32x4*)&sm[SH_Y + 2*128 + ebm];
    const f32x4 y1zv = *(const f32x4*)&sm[SH_Y + 3*128 + ebm];
    #pragma unroll
    for (int ch = 0; ch < 2; ++ch)
      #pragma unroll
      for (int r = 0; r < 4; ++r)
        sm[SH_X + (ebm + r) * 81 + ch*16 + col] =
            A_SC_F * (y0v[r] * aA[ch*4+r] + INV_SQRT3_F * aB[ch*4+r]);
    #pragma unroll
    for (int r = 0; r < 4; ++r) {
      sm[SH_X + (ebm + r)*81 + 32 + col*3 + 0] = A_SC_F * (aC[r]*y1xv[r] + y0v[r]*aD[0+r]);
      sm[SH_X + (ebm + r)*81 + 32 + col*3 + 1] = A_SC_F * (aC[r]*y1yv[r] + y0v[r]*aD[4+r]);
      sm[SH_X + (ebm + r)*81 + 32 + col*3 + 2] = A_SC_F * (aC[r]*y1zv[r] + y0v[r]*aD[8+r]);
    }
  }
  __syncthreads();   // B4: messages visible

  // ---- pg phase (round-7 validated: 2 edges/lane, w-split across waves) ----
  float ps0[8], ps1[8], pt0[4], pt1[4];
  #pragma unroll
  for (int i = 0; i < 8; ++i) { ps0[i] = 0.f; ps1[i] = 0.f; }
  #pragma unroll
  for (int i = 0; i < 4; ++i) { pt0[i] = 0.f; pt1[i] = 0.f; }
  {
    const float* Wp = wpgs + layer * 1536;
    #pragma unroll
    for (int u = 0; u < 32; ++u) {
      const float m0 = sm[SH_X + lane * 81 + u];
      const float m1 = sm[SH_X + (lane + 64) * 81 + u];
      #pragma unroll
      for (int jj = 0; jj < 8; ++jj) {
        const float wv = Wp[u * 48 + wq8 + jj];
        ps0[jj] += m0 * wv; ps1[jj] += m1 * wv;
      }
      #pragma unroll
      for (int wi = 0; wi < 4; ++wi) {
        const float wv = Wp[u * 48 + 32 + wq4 + wi];
        pt0[wi] += m0 * wv; pt1[wi] += m1 * wv;
      }
    }
  }
  float pv0[12], pv1[12];
  #pragma unroll
  for (int i = 0; i < 12; ++i) { pv0[i] = 0.f; pv1[i] = 0.f; }
  {
    const float* Wp = wpgv + layer * 256;
    #pragma unroll
    for (int u = 0; u < 16; ++u) {
      const float a0 = sm[SH_X + lane*81 + 32 + u*3 + 0];
      const float a1 = sm[SH_X + lane*81 + 32 + u*3 + 1];
      const float a2 = sm[SH_X + lane*81 + 32 + u*3 + 2];
      const float b0 = sm[SH_X + (lane+64)*81 + 32 + u*3 + 0];
      const float b1 = sm[SH_X + (lane+64)*81 + 32 + u*3 + 1];
      const float b2 = sm[SH_X + (lane+64)*81 + 32 + u*3 + 2];
      #pragma unroll
      for (int wi = 0; wi < 4; ++wi) {
        const float wv = Wp[u * 16 + wq4 + wi];
        pv0[wi*3+0] += a0*wv; pv0[wi*3+1] += a1*wv; pv0[wi*3+2] += a2*wv;
        pv1[wi*3+0] += b0*wv; pv1[wi*3+1] += b1*wv; pv1[wi*3+2] += b2*wv;
      }
    }
  }
  __syncthreads();   // B5: pg reads done

  #pragma unroll
  for (int jj = 0; jj < 8; ++jj) {
    const float t0 = ps0[jj] * INV_SQRT_S_F;
    const float t1 = ps1[jj] * INV_SQRT_S_F;
    sm[SH_X + lane * 81 + wq8 + jj]        = t0 / (1.0f + __expf(-t0));
    sm[SH_X + (lane + 64) * 81 + wq8 + jj] = t1 / (1.0f + __expf(-t1));
  }
  #pragma unroll
  for (int wi = 0; wi < 4; ++wi) {
    const float g0 = 1.0f / (1.0f + __expf(-pt0[wi] * INV_SQRT_S_F));
    const float g1 = 1.0f / (1.0f + __expf(-pt1[wi] * INV_SQRT_S_F));
    #pragma unroll
    for (int k = 0; k < 3; ++k) {
      sm[SH_X + lane * 81 + 32 + (wq4 + wi)*3 + k]        = g0 * pv0[wi*3+k] * INV_SQRT_V_F;
      sm[SH_X + (lane + 64) * 81 + 32 + (wq4 + wi)*3 + k] = g1 * pv1[wi*3+k] * INV_SQRT_V_F;
    }
  }
  __syncthreads();   // B6: gates visible

  // ---- o = g @ Wlo (w-split), scatter with HW fp32 atomics ----
  float os0[8], os1[8];
  #pragma unroll
  for (int i = 0; i < 8; ++i) { os0[i] = 0.f; os1[i] = 0.f; }
  {
    const float* Wp = wlos + layer * 1024;
    #pragma unroll
    for (int u = 0; u < 32; ++u) {
      const float g0 = sm[SH_X + lane * 81 + u];
      const float g1 = sm[SH_X + (lane + 64) * 81 + u];
      #pragma unroll
      for (int wi = 0; wi < 8; ++wi) {
        const float wv = Wp[u * 32 + wq8 + wi];
        os0[wi] += g0 * wv; os1[wi] += g1 * wv;
      }
    }
  }
  float ov0[12], ov1[12];
  #pragma unroll
  for (int i = 0; i < 12; ++i) { ov0[i] = 0.f; ov1[i] = 0.f; }
  {
    const float* Wp = wlov + layer * 256;
    #pragma unroll
    for (int u = 0; u < 16; ++u) {
      const float a0 = sm[SH_X + lane*81 + 32 + u*3 + 0];
      const float a1 = sm[SH_X + lane*81 + 32 + u*3 + 1];
      const float a2 = sm[SH_X + lane*81 + 32 + u*3 + 2];
      const float b0 = sm[SH_X + (lane+64)*81 + 32 + u*3 + 0];
      const float b1 = sm[SH_X + (lane+64)*81 + 32 + u*3 + 1];
      const float b2 = sm[SH_X + (lane+64)*81 + 32 + u*3 + 2];
      #pragma unroll
      for (int wi = 0; wi < 4; ++wi) {
        const float wv = Wp[u * 16 + wq4 + wi];
        ov0[wi*3+0] += a0*wv; ov0[wi*3+1] += a1*wv; ov0[wi*3+2] += a2*wv;
        ov1[wi*3+0] += b0*wv; ov1[wi*3+1] += b1*wv; ov1[wi*3+2] += b2*wv;
      }
    }
  }
  if (ok0) {
    float* sd = sn + (size_t)dn0 * 32 + wq8;
    #pragma unroll
    for (int wi = 0; wi < 8; ++wi) unsafeAtomicAdd(&sd[wi], os0[wi] * INV_SQRT_S_F);
    float* vd = vn + (size_t)dn0 * 48 + wq4 * 3;
    #pragma unroll
    for (int j = 0; j < 12; ++j) unsafeAtomicAdd(&vd[j], ov0[j] * INV_SQRT_V_F);
  }
  if (ok1) {
    float* sd = sn + (size_t)dn1 * 32 + wq8;
    #pragma unroll
    for (int wi = 0; wi < 8; ++wi) unsafeAtomicAdd(&sd[wi], os1[wi] * INV_SQRT_S_F);
    float* vd = vn + (size_t)dn1 * 48 + wq4 * 3;
    #pragma unroll
    for (int j = 0; j < 12; ++j) unsafeAtomicAdd(&vd[j], ov1[j] * INV_SQRT_V_F);
  }
}

// out[n,k] = coeffs[n] @ M  — FP32 OUTPUT
__global__ __launch_bounds__(256) void final_kernel(
    const float* __restrict__ s0, const float* __restrict__ v0,
    const float* __restrict__ wos, const float* __restrict__ wov,
    const float* __restrict__ wf, float* __restrict__ out, int N)
{
  int n = blockIdx.x * 256 + threadIdx.x;
  if (n >= N) return;
  float cs = 0.f;
  #pragma unroll
  for (int u = 0; u < 32; ++u) cs += s0[n * 32 + u] * wos[u];
  cs *= INV_SQRT_S_F;
  float cv0 = 0.f, cv1 = 0.f, cv2 = 0.f;
  #pragma unroll
  for (int u = 0; u < 16; ++u) {
    const float wv = wov[u];
    cv0 += v0[n * 48 + u * 3 + 0] * wv;
    cv1 += v0[n * 48 + u * 3 + 1] * wv;
    cv2 += v0[n * 48 + u * 3 + 2] * wv;
  }
  cv0 *= INV_SQRT_V_F; cv1 *= INV_SQRT_V_F; cv2 *= INV_SQRT_V_F;
  #pragma unroll
  for (int k = 0; k < 3; ++k) {
    out[n * 3 + k] = cs  * wf[OFF_M + k]
                   + cv0 * wf[OFF_M + 3 + k]
                   + cv1 * wf[OFF_M + 6 + k]
                   + cv2 * wf[OFF_M + 9 + k];
  }
}

extern "C" void kernel_launch(void* const* d_in, const int* in_sizes, int n_in,
                              void* d_out, int out_size, void* d_ws, size_t ws_size,
                              hipStream_t stream)
{
  (void)n_in; (void)out_size; (void)ws_size;
  const float* x    = (const float*)d_in[0];
  const int*   ei   = (const int*)d_in[1];
  const float* ed   = (const float*)d_in[2];
  const float* esh  = (const float*)d_in[3];
  const float* dirs = (const float*)d_in[4];
  const float* wins = (const float*)d_in[5];
  const float* winv = (const float*)d_in[6];
  const float* wscs = (const float*)d_in[7];
  const float* wscv = (const float*)d_in[8];
  const float* wr1  = (const float*)d_in[9];
  const float* br1  = (const float*)d_in[10];
  const float* wr2  = (const float*)d_in[11];
  const float* br2  = (const float*)d_in[12];
  const float* wpgs = (const float*)d_in[13];
  const float* wpgv = (const float*)d_in[14];
  const float* wlos = (const float*)d_in[15];
  const float* wlov = (const float*)d_in[16];
  const float* wos  = (const float*)d_in[17];
  const float* wov  = (const float*)d_in[18];

  const int N = in_sizes[0] / 6;
  const int E = in_sizes[1] / 2;

  float* wf = (float*)d_ws;
  unsigned short* fhi = (unsigned short*)(wf + OFF_FRAGHI);
  unsigned short* flo = (unsigned short*)(wf + OFF_FRAGLO);
  float* s0 = wf + OFF_NODE;
  float* v0 = s0 + (size_t)N * 32;
  float* s1 = v0 + (size_t)N * 48;
  float* v1 = s1 + (size_t)N * 32;

  const int nodeBlocks = (N * 80 + 255) / 256;
  const int edgeBlocks = (E + 127) / 128;
  const int finBlocks  = (N + 255) / 256;

  fragpack_kernel<<<(147456 + 255) / 256, 256, 0, stream>>>(wr2, fhi, flo);
  mmat_kernel<<<1, 64, 0, stream>>>(dirs, wf);
  node_init_kernel<<<nodeBlocks, 256, 0, stream>>>(x, wins, winv, s0, v0, N);

  // layer 0: s0/v0 -> s1/v1
  selfmix_kernel<<<nodeBlocks, 256, 0, stream>>>(s0, v0, s1, v1, wscs, wscv, 0, N);
  edge_kernel<<<edgeBlocks, 256, 0, stream>>>(ei, ed, esh, s0, v0, s1, v1,
      wr1, br1, fhi, flo, br2, wpgs, wpgv, wlos, wlov, 0, E, N);
  // layer 1: s1/v1 -> s0/v0
  selfmix_kernel<<<nodeBlocks, 256, 0, stream>>>(s1, v1, s0, v0, wscs, wscv, 1, N);
  edge_kernel<<<edgeBlocks, 256, 0, stream>>>(ei, ed, esh, s1, v1, s0, v0,
      wr1, br1, fhi, flo, br2, wpgs, wpgv, wlos, wlov, 1, E, N);

  final_kernel<<<finBlocks, 256, 0, stream>>>(s0, v0, wos, wov, wf,
      (float*)d_out, N);
}

// Round 13
// 654.401 us; speedup vs baseline: 1.4375x; 1.0835x over previous
//
#include <hip/hip_runtime.h>

// ---------------- constants ----------------
#define CUTOFF_F     0.35f
#define PI_F         3.14159265358979323846f
#define SQRT3_F      1.7320508075688772f
#define INV_SQRT3_F  0.5773502691896258f
#define INV_SQRT_S_F 0.17677669529663687f   // 1/sqrt(32)
#define INV_SQRT_V_F 0.25f                  // 1/sqrt(16)
#define A_SC_F       0.14433756729740643f   // 1/sqrt(48)

// ws layout (floats): [0..12) M | fragHi | fragLo | node buffers
#define OFF_M      0
#define OFF_FRAGHI 16        // 147456 ushort = 73728 floats
#define OFF_FRAGLO 73744
#define OFF_NODE   147472

// LDS union (floats)
#define SH_H    0                 // 128*33 = 4224 (hext, stride 33)
#define SH_SJ   4224              // 32*128 = 4096
#define SH_VD   (4224+4096)       // 16*128 = 2048
#define SH_VJ   (4224+6144)       // 48*128 = 6144
#define SH_X    4224              // 128*81 = 10368 (aliases SJ/VD/VJ after B3)
#define SH_Y    (4224+12288)      // 4*128 = 512
#define SH_TOT  (4224+12288+512)  // 17024 floats = 68096 B -> 2 blocks/CU (LDS-limited)

typedef __attribute__((ext_vector_type(8))) short bshort8;
typedef __attribute__((ext_vector_type(4))) float f32x4;

static __device__ __forceinline__ float b2f(unsigned short u) {
  union { unsigned int i; float f; } x; x.i = ((unsigned int)u) << 16; return x.f;
}
static __device__ __forceinline__ unsigned short f2b(float f) {
  union { float f; unsigned int i; } x; x.f = f;
  unsigned int i = x.i;
  return (unsigned short)((i + 0x7FFFu + ((i >> 16) & 1u)) >> 16);
}
// compensated bf16 product: 2-MFMA chain (residuals) + 1 independent MFMA
static __device__ __forceinline__ f32x4 mfma_c(bshort8 ah, bshort8 al, bshort8 bh, bshort8 bl) {
  f32x4 z = {0.f, 0.f, 0.f, 0.f};
  z = __builtin_amdgcn_mfma_f32_16x16x32_bf16(al, bh, z, 0, 0, 0);
  z = __builtin_amdgcn_mfma_f32_16x16x32_bf16(ah, bl, z, 0, 0, 0);
  f32x4 m = {0.f, 0.f, 0.f, 0.f};
  m = __builtin_amdgcn_mfma_f32_16x16x32_bf16(ah, bh, m, 0, 0, 0);
  return z + m;
}

// pack Wr2 into MFMA B-fragments, compensated bf16 (hi + lo residual)
// frag idx = ((layer*144 + t)*64 + lane)*8 + i ; B[k=quad*8+i][col] = W[c][j]
__global__ __launch_bounds__(256) void fragpack_kernel(
    const float* __restrict__ wr2, unsigned short* __restrict__ fhi,
    unsigned short* __restrict__ flo)
{
  int idx = blockIdx.x * 256 + threadIdx.x;
  if (idx >= 147456) return;
  int i    = idx & 7;
  int lane = (idx >> 3) & 63;
  int tl   = idx >> 9;
  int t    = tl % 144;
  int layer = tl / 144;
  int c = (lane >> 4) * 8 + i;
  int j = t * 16 + (lane & 15);
  float w = wr2[((size_t)(layer * 32 + c)) * 2304 + j];
  unsigned short h = f2b(w);
  fhi[idx] = h;
  flo[idx] = f2b(w - b2f(h));
}

// M[c][k] = (1/256) * Y[:,c] . dirs[:,k]
__global__ void mmat_kernel(const float* __restrict__ dirs, float* __restrict__ wf) {
  int t = threadIdx.x;
  if (t >= 12) return;
  int c = t / 3, k = t - c * 3;
  float acc = 0.f;
  for (int p = 0; p < 256; ++p) {
    float dk = dirs[p * 3 + k];
    acc += (c == 0) ? dk : dirs[p * 3 + (c - 1)] * dk;
  }
  wf[OFF_M + t] = acc * ((c == 0) ? (1.0f / 256.0f) : (SQRT3_F / 256.0f));
}

__global__ __launch_bounds__(256) void node_init_kernel(
    const float* __restrict__ x, const float* __restrict__ wins,
    const float* __restrict__ winv,
    float* __restrict__ s0, float* __restrict__ v0, int N)
{
  int t = blockIdx.x * 256 + threadIdx.x;
  int n = t / 80; int slot = t - n * 80;
  if (n >= N) return;
  if (slot < 32) {
    float acc = 0.f;
    #pragma unroll
    for (int d = 0; d < 3; ++d) acc += x[n * 6 + d] * wins[d * 32 + slot];
    s0[n * 32 + slot] = acc * INV_SQRT3_F;
  } else {
    int j = slot - 32; int u = j / 3; int k = j - u * 3;
    v0[n * 48 + j] = x[n * 6 + 3 + k] * winv[u];
  }
}

__global__ __launch_bounds__(256) void selfmix_kernel(
    const float* __restrict__ sc, const float* __restrict__ vc,
    float* __restrict__ sn, float* __restrict__ vn,
    const float* __restrict__ wscs, const float* __restrict__ wscv,
    int layer, int N)
{
  int t = blockIdx.x * 256 + threadIdx.x;
  int n = t / 80; int slot = t - n * 80;
  if (n >= N) return;
  if (slot < 32) {
    const float* W = wscs + layer * 1024;
    float acc = 0.f;
    #pragma unroll
    for (int u = 0; u < 32; ++u) acc += sc[n * 32 + u] * W[u * 32 + slot];
    sn[n * 32 + slot] = acc * INV_SQRT_S_F;
  } else {
    int j = slot - 32; int w = j / 3; int k = j - w * 3;
    const float* W = wscv + layer * 256;
    float acc = 0.f;
    #pragma unroll
    for (int u = 0; u < 16; ++u) acc += vc[n * 48 + u * 3 + k] * W[u * 16 + w];
    vn[n * 48 + j] = acc * INV_SQRT_V_F;
  }
}

// ---------------- edge kernel: MFMA h-first, 128 edges/block, 2 M-tiles/wave --
// ROUND-10 PASSING STRUCTURE VERBATIM. Only change: __launch_bounds__(256,1)
// so the allocator gets the ~190-reg live set without spilling. LDS (68KB)
// limits occupancy to 2 blocks/CU either way, so the cap bought nothing.
__global__ __launch_bounds__(256, 1) void edge_kernel(
    const int* __restrict__ ei, const float* __restrict__ ed,
    const float* __restrict__ esh,
    const float* __restrict__ sc, const float* __restrict__ vc,
    float* __restrict__ sn, float* __restrict__ vn,
    const float* __restrict__ wr1, const float* __restrict__ br1,
    const unsigned short* __restrict__ wfh, const unsigned short* __restrict__ wfl,
    const float* __restrict__ br2,
    const float* __restrict__ wpgs, const float* __restrict__ wpgv,
    const float* __restrict__ wlos, const float* __restrict__ wlov,
    int layer, int E, int N)
{
  __shared__ __align__(16) float sm[SH_TOT];

  const int tid  = threadIdx.x;
  const int lane = tid & 63;
  const int q    = tid >> 6;
  const int col  = lane & 15;
  const int quad = lane >> 4;
  const int wq8  = q * 8;
  const int wq4  = q * 4;
  const int ge0  = blockIdx.x * 128 + lane;     // edge A (block-local = lane)
  const int ge1  = ge0 + 64;                    // edge B (block-local = lane+64)
  const bool ok0 = ge0 < E, ok1 = ge1 < E;
  const int eL0  = ok0 ? ge0 : E - 1;
  const int eL1  = ok1 ? ge1 : E - 1;
  int sn0 = ei[eL0];     sn0 = (sn0 < 0) ? 0 : (sn0 >= N ? N - 1 : sn0);
  int sn1 = ei[eL1];     sn1 = (sn1 < 0) ? 0 : (sn1 >= N ? N - 1 : sn1);
  int dn0 = ei[E + eL0]; dn0 = (dn0 < 0) ? 0 : (dn0 >= N ? N - 1 : dn0);
  int dn1 = ei[E + eL1]; dn1 = (dn1 < 0) ? 0 : (dn1 >= N ? N - 1 : dn1);
  const float y00 = esh[eL0*4+0], y0x = esh[eL0*4+1], y0y = esh[eL0*4+2], y0z = esh[eL0*4+3];
  const float y10 = esh[eL1*4+0], y1x = esh[eL1*4+1], y1y = esh[eL1*4+2], y1z = esh[eL1*4+3];

  // ---- stage h (wave-split over j, 2 edges/lane) ----
  {
    const float d0 = ed[eL0], d1 = ed[eL1];
    const float inv_w = 12.0f / CUTOFF_F;
    float cut0 = (d0 < CUTOFF_F) ? 0.5f * (__cosf(d0 * (PI_F / CUTOFF_F)) + 1.0f) : 0.0f;
    float cut1 = (d1 < CUTOFF_F) ? 0.5f * (__cosf(d1 * (PI_F / CUTOFF_F)) + 1.0f) : 0.0f;
    float rb0[6], rb1[6];
    #pragma unroll
    for (int r = 0; r < 6; ++r) {
      float z0 = (d0 - 0.07f * (float)r) * inv_w;
      float z1 = (d1 - 0.07f * (float)r) * inv_w;
      rb0[r] = __expf(-0.5f * z0 * z0) * cut0;
      rb1[r] = __expf(-0.5f * z1 * z1) * cut1;
    }
    const float* W1p = wr1 + layer * 192;
    const float* B1p = br1 + layer * 32;
    #pragma unroll
    for (int jj = 0; jj < 8; ++jj) {
      const int j = wq8 + jj;
      float z0 = B1p[j], z1 = z0;
      #pragma unroll
      for (int r = 0; r < 6; ++r) {
        const float wv = W1p[r * 32 + j];
        z0 += rb0[r] * wv; z1 += rb1[r] * wv;
      }
      sm[SH_H + lane * 33 + j]        = z0 / (1.0f + __expf(-z0));
      sm[SH_H + (lane + 64) * 33 + j] = z1 / (1.0f + __expf(-z1));
    }
  }
  // ---- stage sSj (wave-split over u, 2 edges/lane) ----
  {
    const f32x4* p0 = (const f32x4*)(sc + (size_t)sn0 * 32 + wq8);
    f32x4 a = p0[0], b = p0[1];
    #pragma unroll
    for (int i = 0; i < 4; ++i) {
      sm[SH_SJ + (wq8 + i) * 128 + lane]     = a[i];
      sm[SH_SJ + (wq8 + 4 + i) * 128 + lane] = b[i];
    }
    const f32x4* p1 = (const f32x4*)(sc + (size_t)sn1 * 32 + wq8);
    a = p1[0]; b = p1[1];
    #pragma unroll
    for (int i = 0; i < 4; ++i) {
      sm[SH_SJ + (wq8 + i) * 128 + lane + 64]     = a[i];
      sm[SH_SJ + (wq8 + 4 + i) * 128 + lane + 64] = b[i];
    }
  }
  // ---- stage sVj + sVd ----
  {
    const f32x4* vp = (const f32x4*)(vc + (size_t)sn0 * 48 + wq4 * 3);
    f32x4 a = vp[0], b = vp[1], c = vp[2];
    float vt[12];
    #pragma unroll
    for (int i = 0; i < 4; ++i) { vt[i] = a[i]; vt[4+i] = b[i]; vt[8+i] = c[i]; }
    #pragma unroll
    for (int i = 0; i < 12; ++i) sm[SH_VJ + (wq4 * 3 + i) * 128 + lane] = vt[i];
    #pragma unroll
    for (int u = 0; u < 4; ++u)
      sm[SH_VD + (wq4 + u) * 128 + lane] =
          vt[u*3] * y0x + vt[u*3+1] * y0y + vt[u*3+2] * y0z;
    vp = (const f32x4*)(vc + (size_t)sn1 * 48 + wq4 * 3);
    a = vp[0]; b = vp[1]; c = vp[2];
    #pragma unroll
    for (int i = 0; i < 4; ++i) { vt[i] = a[i]; vt[4+i] = b[i]; vt[8+i] = c[i]; }
    #pragma unroll
    for (int i = 0; i < 12; ++i) sm[SH_VJ + (wq4 * 3 + i) * 128 + lane + 64] = vt[i];
    #pragma unroll
    for (int u = 0; u < 4; ++u)
      sm[SH_VD + (wq4 + u) * 128 + lane + 64] =
          vt[u*3] * y1x + vt[u*3+1] * y1y + vt[u*3+2] * y1z;
  }
  if (q == 0) {
    sm[SH_Y + 0*128 + lane] = y00;  sm[SH_Y + 1*128 + lane] = y0x;
    sm[SH_Y + 2*128 + lane] = y0y;  sm[SH_Y + 3*128 + lane] = y0z;
    sm[SH_Y + 0*128 + lane + 64] = y10;  sm[SH_Y + 1*128 + lane + 64] = y1x;
    sm[SH_Y + 2*128 + lane + 64] = y1y;  sm[SH_Y + 3*128 + lane + 64] = y1z;
  }
  __syncthreads();   // B1: staging done

  // ---- A-fragments for this wave's 2 M-tiles (edges [32q+16mt, +16)) ----
  bshort8 a0h, a0l, a1h, a1l;
  #pragma unroll
  for (int i = 0; i < 8; ++i) {
    float h0 = sm[SH_H + (32*q + col) * 33 + quad * 8 + i];
    float h1 = sm[SH_H + (32*q + 16 + col) * 33 + quad * 8 + i];
    unsigned short hh0 = f2b(h0), hh1 = f2b(h1);
    a0h[i] = (short)hh0; a0l[i] = (short)f2b(h0 - b2f(hh0));
    a1h[i] = (short)hh1; a1l[i] = (short)f2b(h1 - b2f(hh1));
  }

  const bshort8* wbh = (const bshort8*)wfh + (size_t)layer * 144 * 64 + lane;
  const bshort8* wbl = (const bshort8*)wfl + (size_t)layer * 144 * 64 + lane;
  const float* br2L = br2 + (size_t)layer * 2304;
  const int eb0 = 32*q + quad * 4;   // C-reg base edge, M-tile 0
  const int eb1 = eb0 + 16;          // M-tile 1

  float accA0[8], accA1[8], accB0[8], accB1[8];
  float accC0[4], accC1[4], accD0[12], accD1[12];
  #pragma unroll
  for (int i = 0; i < 8; ++i) { accA0[i]=0.f; accA1[i]=0.f; accB0[i]=0.f; accB1[i]=0.f; }
  #pragma unroll
  for (int i = 0; i < 4; ++i) { accC0[i]=0.f; accC1[i]=0.f; }
  #pragma unroll
  for (int i = 0; i < 12; ++i) { accD0[i]=0.f; accD1[i]=0.f; }

  // ---- W1/W3 loop: tiles 2u, 2u+1, 96+u; prefetch next iteration ----
  {
    bshort8 h0 = wbh[0*64],  l0 = wbl[0*64];
    bshort8 h1 = wbh[1*64],  l1 = wbl[1*64];
    bshort8 h2 = wbh[96*64], l2 = wbl[96*64];
    for (int u = 0; u < 32; ++u) {
      const bshort8 c0h=h0, c0l=l0, c1h=h1, c1l=l1, c2h=h2, c2l=l2;
      if (u < 31) {
        h0 = wbh[(size_t)(2*u+2)*64];  l0 = wbl[(size_t)(2*u+2)*64];
        h1 = wbh[(size_t)(2*u+3)*64];  l1 = wbl[(size_t)(2*u+3)*64];
        h2 = wbh[(size_t)(97+u)*64];   l2 = wbl[(size_t)(97+u)*64];
      }
      const float bb0 = br2L[(2*u)*16 + col];
      const float bb1 = br2L[(2*u+1)*16 + col];
      const float bb2 = br2L[(96+u)*16 + col];
      const f32x4 sj0 = *(const f32x4*)&sm[SH_SJ + u*128 + eb0];
      const f32x4 sj1 = *(const f32x4*)&sm[SH_SJ + u*128 + eb1];
      f32x4 t00 = mfma_c(a0h, a0l, c0h, c0l);
      f32x4 t01 = mfma_c(a1h, a1l, c0h, c0l);
      f32x4 t10 = mfma_c(a0h, a0l, c1h, c1l);
      f32x4 t11 = mfma_c(a1h, a1l, c1h, c1l);
      f32x4 t20 = mfma_c(a0h, a0l, c2h, c2l);
      f32x4 t21 = mfma_c(a1h, a1l, c2h, c2l);
      #pragma unroll
      for (int r = 0; r < 4; ++r) {
        accA0[r]   += sj0[r] * (t00[r] + bb0);
        accA1[r]   += sj1[r] * (t01[r] + bb0);
        accA0[4+r] += sj0[r] * (t10[r] + bb1);
        accA1[4+r] += sj1[r] * (t11[r] + bb1);
        accC0[r]   += sj0[r] * (t20[r] + bb2);
        accC1[r]   += sj1[r] * (t21[r] + bb2);
      }
    }
  }
  // ---- W2/W4 loop: tiles 64+2u, 65+2u, 128+u ----
  {
    bshort8 h0 = wbh[64*64],  l0 = wbl[64*64];
    bshort8 h1 = wbh[65*64],  l1 = wbl[65*64];
    bshort8 h2 = wbh[128*64], l2 = wbl[128*64];
    for (int u = 0; u < 16; ++u) {
      const bshort8 c0h=h0, c0l=l0, c1h=h1, c1l=l1, c2h=h2, c2l=l2;
      if (u < 15) {
        h0 = wbh[(size_t)(66+2*u)*64];  l0 = wbl[(size_t)(66+2*u)*64];
        h1 = wbh[(size_t)(67+2*u)*64];  l1 = wbl[(size_t)(67+2*u)*64];
        h2 = wbh[(size_t)(129+u)*64];   l2 = wbl[(size_t)(129+u)*64];
      }
      const float bb0 = br2L[(64+2*u)*16 + col];
      const float bb1 = br2L[(65+2*u)*16 + col];
      const float bb2 = br2L[(128+u)*16 + col];
      const f32x4 vd0 = *(const f32x4*)&sm[SH_VD + u*128 + eb0];
      const f32x4 vd1 = *(const f32x4*)&sm[SH_VD + u*128 + eb1];
      f32x4 t00 = mfma_c(a0h, a0l, c0h, c0l);
      f32x4 t01 = mfma_c(a1h, a1l, c0h, c0l);
      f32x4 t10 = mfma_c(a0h, a0l, c1h, c1l);
      f32x4 t11 = mfma_c(a1h, a1l, c1h, c1l);
      f32x4 t20 = mfma_c(a0h, a0l, c2h, c2l);
      f32x4 t21 = mfma_c(a1h, a1l, c2h, c2l);
      #pragma unroll
      for (int r = 0; r < 4; ++r) {
        accB0[r]   += vd0[r] * (t00[r] + bb0);
        accB1[r]   += vd1[r] * (t01[r] + bb0);
        accB0[4+r] += vd0[r] * (t10[r] + bb1);
        accB1[4+r] += vd1[r] * (t11[r] + bb1);
      }
      #pragma unroll
      for (int k = 0; k < 3; ++k) {
        const f32x4 vj0 = *(const f32x4*)&sm[SH_VJ + (u*3+k)*128 + eb0];
        const f32x4 vj1 = *(const f32x4*)&sm[SH_VJ + (u*3+k)*128 + eb1];
        #pragma unroll
        for (int r = 0; r < 4; ++r) {
          accD0[k*4+r] += vj0[r] * (t20[r] + bb2);
          accD1[k*4+r] += vj1[r] * (t21[r] + bb2);
        }
      }
    }
  }
  __syncthreads();   // B3: all waves done reading SJ/VD/VJ -> sX may overwrite

  // ---- messages into sX (per M-tile; y via sY which is NOT aliased) ----
  #pragma unroll
  for (int mt = 0; mt < 2; ++mt) {
    const int ebm = (mt == 0) ? eb0 : eb1;
    const float* aA = (mt == 0) ? accA0 : accA1;
    const float* aB = (mt == 0) ? accB0 : accB1;
    const float* aC = (mt == 0) ? accC0 : accC1;
    const float* aD = (mt == 0) ? accD0 : accD1;
    const f32x4 y0v  = *(const f32x4*)&sm[SH_Y + 0*128 + ebm];
    const f32x4 y1xv = *(const f32x4*)&sm[SH_Y + 1*128 + ebm];
    const f32x4 y1yv = *(const f32x4*)&sm[SH_Y + 2*128 + ebm];
    const f32x4 y1zv = *(const f32x4*)&sm[SH_Y + 3*128 + ebm];
    #pragma unroll
    for (int ch = 0; ch < 2; ++ch)
      #pragma unroll
      for (int r = 0; r < 4; ++r)
        sm[SH_X + (ebm + r) * 81 + ch*16 + col] =
            A_SC_F * (y0v[r] * aA[ch*4+r] + INV_SQRT3_F * aB[ch*4+r]);
    #pragma unroll
    for (int r = 0; r < 4; ++r) {
      sm[SH_X + (ebm + r)*81 + 32 + col*3 + 0] = A_SC_F * (aC[r]*y1xv[r] + y0v[r]*aD[0+r]);
      sm[SH_X + (ebm + r)*81 + 32 + col*3 + 1] = A_SC_F * (aC[r]*y1yv[r] + y0v[r]*aD[4+r]);
      sm[SH_X + (ebm + r)*81 + 32 + col*3 + 2] = A_SC_F * (aC[r]*y1zv[r] + y0v[r]*aD[8+r]);
    }
  }
  __syncthreads();   // B4: messages visible

  // ---- pg phase (2 edges/lane, w-split across waves) ----
  float ps0[8], ps1[8], pt0[4], pt1[4];
  #pragma unroll
  for (int i = 0; i < 8; ++i) { ps0[i] = 0.f; ps1[i] = 0.f; }
  #pragma unroll
  for (int i = 0; i < 4; ++i) { pt0[i] = 0.f; pt1[i] = 0.f; }
  {
    const float* Wp = wpgs + layer * 1536;
    #pragma unroll
    for (int u = 0; u < 32; ++u) {
      const float m0 = sm[SH_X + lane * 81 + u];
      const float m1 = sm[SH_X + (lane + 64) * 81 + u];
      #pragma unroll
      for (int jj = 0; jj < 8; ++jj) {
        const float wv = Wp[u * 48 + wq8 + jj];
        ps0[jj] += m0 * wv; ps1[jj] += m1 * wv;
      }
      #pragma unroll
      for (int wi = 0; wi < 4; ++wi) {
        const float wv = Wp[u * 48 + 32 + wq4 + wi];
        pt0[wi] += m0 * wv; pt1[wi] += m1 * wv;
      }
    }
  }
  float pv0[12], pv1[12];
  #pragma unroll
  for (int i = 0; i < 12; ++i) { pv0[i] = 0.f; pv1[i] = 0.f; }
  {
    const float* Wp = wpgv + layer * 256;
    #pragma unroll
    for (int u = 0; u < 16; ++u) {
      const float a0 = sm[SH_X + lane*81 + 32 + u*3 + 0];
      const float a1 = sm[SH_X + lane*81 + 32 + u*3 + 1];
      const float a2 = sm[SH_X + lane*81 + 32 + u*3 + 2];
      const float b0 = sm[SH_X + (lane+64)*81 + 32 + u*3 + 0];
      const float b1 = sm[SH_X + (lane+64)*81 + 32 + u*3 + 1];
      const float b2 = sm[SH_X + (lane+64)*81 + 32 + u*3 + 2];
      #pragma unroll
      for (int wi = 0; wi < 4; ++wi) {
        const float wv = Wp[u * 16 + wq4 + wi];
        pv0[wi*3+0] += a0*wv; pv0[wi*3+1] += a1*wv; pv0[wi*3+2] += a2*wv;
        pv1[wi*3+0] += b0*wv; pv1[wi*3+1] += b1*wv; pv1[wi*3+2] += b2*wv;
      }
    }
  }
  __syncthreads();   // B5: pg reads done

  #pragma unroll
  for (int jj = 0; jj < 8; ++jj) {
    const float t0 = ps0[jj] * INV_SQRT_S_F;
    const float t1 = ps1[jj] * INV_SQRT_S_F;
    sm[SH_X + lane * 81 + wq8 + jj]        = t0 / (1.0f + __expf(-t0));
    sm[SH_X + (lane + 64) * 81 + wq8 + jj] = t1 / (1.0f + __expf(-t1));
  }
  #pragma unroll
  for (int wi = 0; wi < 4; ++wi) {
    const float g0 = 1.0f / (1.0f + __expf(-pt0[wi] * INV_SQRT_S_F));
    const float g1 = 1.0f / (1.0f + __expf(-pt1[wi] * INV_SQRT_S_F));
    #pragma unroll
    for (int k = 0; k < 3; ++k) {
      sm[SH_X + lane * 81 + 32 + (wq4 + wi)*3 + k]        = g0 * pv0[wi*3+k] * INV_SQRT_V_F;
      sm[SH_X + (lane + 64) * 81 + 32 + (wq4 + wi)*3 + k] = g1 * pv1[wi*3+k] * INV_SQRT_V_F;
    }
  }
  __syncthreads();   // B6: gates visible

  // ---- o = g @ Wlo (w-split), scatter with HW fp32 atomics ----
  float os0[8], os1[8];
  #pragma unroll
  for (int i = 0; i < 8; ++i) { os0[i] = 0.f; os1[i] = 0.f; }
  {
    const float* Wp = wlos + layer * 1024;
    #pragma unroll
    for (int u = 0; u < 32; ++u) {
      const float g0 = sm[SH_X + lane * 81 + u];
      const float g1 = sm[SH_X + (lane + 64) * 81 + u];
      #pragma unroll
      for (int wi = 0; wi < 8; ++wi) {
        const float wv = Wp[u * 32 + wq8 + wi];
        os0[wi] += g0 * wv; os1[wi] += g1 * wv;
      }
    }
  }
  float ov0[12], ov1[12];
  #pragma unroll
  for (int i = 0; i < 12; ++i) { ov0[i] = 0.f; ov1[i] = 0.f; }
  {
    const float* Wp = wlov + layer * 256;
    #pragma unroll
    for (int u = 0; u < 16; ++u) {
      const float a0 = sm[SH_X + lane*81 + 32 + u*3 + 0];
      const float a1 = sm[SH_X + lane*81 + 32 + u*3 + 1];
      const float a2 = sm[SH_X + lane*81 + 32 + u*3 + 2];
      const float b0 = sm[SH_X + (lane+64)*81 + 32 + u*3 + 0];
      const float b1 = sm[SH_X + (lane+64)*81 + 32 + u*3 + 1];
      const float b2 = sm[SH_X + (lane+64)*81 + 32 + u*3 + 2];
      #pragma unroll
      for (int wi = 0; wi < 4; ++wi) {
        const float wv = Wp[u * 16 + wq4 + wi];
        ov0[wi*3+0] += a0*wv; ov0[wi*3+1] += a1*wv; ov0[wi*3+2] += a2*wv;
        ov1[wi*3+0] += b0*wv; ov1[wi*3+1] += b1*wv; ov1[wi*3+2] += b2*wv;
      }
    }
  }
  if (ok0) {
    float* sd = sn + (size_t)dn0 * 32 + wq8;
    #pragma unroll
    for (int wi = 0; wi < 8; ++wi) unsafeAtomicAdd(&sd[wi], os0[wi] * INV_SQRT_S_F);
    float* vd = vn + (size_t)dn0 * 48 + wq4 * 3;
    #pragma unroll
    for (int j = 0; j < 12; ++j) unsafeAtomicAdd(&vd[j], ov0[j] * INV_SQRT_V_F);
  }
  if (ok1) {
    float* sd = sn + (size_t)dn1 * 32 + wq8;
    #pragma unroll
    for (int wi = 0; wi < 8; ++wi) unsafeAtomicAdd(&sd[wi], os1[wi] * INV_SQRT_S_F);
    float* vd = vn + (size_t)dn1 * 48 + wq4 * 3;
    #pragma unroll
    for (int j = 0; j < 12; ++j) unsafeAtomicAdd(&vd[j], ov1[j] * INV_SQRT_V_F);
  }
}

// out[n,k] = coeffs[n] @ M  — FP32 OUTPUT
__global__ __launch_bounds__(256) void final_kernel(
    const float* __restrict__ s0, const float* __restrict__ v0,
    const float* __restrict__ wos, const float* __restrict__ wov,
    const float* __restrict__ wf, float* __restrict__ out, int N)
{
  int n = blockIdx.x * 256 + threadIdx.x;
  if (n >= N) return;
  float cs = 0.f;
  #pragma unroll
  for (int u = 0; u < 32; ++u) cs += s0[n * 32 + u] * wos[u];
  cs *= INV_SQRT_S_F;
  float cv0 = 0.f, cv1 = 0.f, cv2 = 0.f;
  #pragma unroll
  for (int u = 0; u < 16; ++u) {
    const float wv = wov[u];
    cv0 += v0[n * 48 + u * 3 + 0] * wv;
    cv1 += v0[n * 48 + u * 3 + 1] * wv;
    cv2 += v0[n * 48 + u * 3 + 2] * wv;
  }
  cv0 *= INV_SQRT_V_F; cv1 *= INV_SQRT_V_F; cv2 *= INV_SQRT_V_F;
  #pragma unroll
  for (int k = 0; k < 3; ++k) {
    out[n * 3 + k] = cs  * wf[OFF_M + k]
                   + cv0 * wf[OFF_M + 3 + k]
                   + cv1 * wf[OFF_M + 6 + k]
                   + cv2 * wf[OFF_M + 9 + k];
  }
}

extern "C" void kernel_launch(void* const* d_in, const int* in_sizes, int n_in,
                              void* d_out, int out_size, void* d_ws, size_t ws_size,
                              hipStream_t stream)
{
  (void)n_in; (void)out_size; (void)ws_size;
  const float* x    = (const float*)d_in[0];
  const int*   ei   = (const int*)d_in[1];
  const float* ed   = (const float*)d_in[2];
  const float* esh  = (const float*)d_in[3];
  const float* dirs = (const float*)d_in[4];
  const float* wins = (const float*)d_in[5];
  const float* winv = (const float*)d_in[6];
  const float* wscs = (const float*)d_in[7];
  const float* wscv = (const float*)d_in[8];
  const float* wr1  = (const float*)d_in[9];
  const float* br1  = (const float*)d_in[10];
  const float* wr2  = (const float*)d_in[11];
  const float* br2  = (const float*)d_in[12];
  const float* wpgs = (const float*)d_in[13];
  const float* wpgv = (const float*)d_in[14];
  const float* wlos = (const float*)d_in[15];
  const float* wlov = (const float*)d_in[16];
  const float* wos  = (const float*)d_in[17];
  const float* wov  = (const float*)d_in[18];

  const int N = in_sizes[0] / 6;
  const int E = in_sizes[1] / 2;

  float* wf = (float*)d_ws;
  unsigned short* fhi = (unsigned short*)(wf + OFF_FRAGHI);
  unsigned short* flo = (unsigned short*)(wf + OFF_FRAGLO);
  float* s0 = wf + OFF_NODE;
  float* v0 = s0 + (size_t)N * 32;
  float* s1 = v0 + (size_t)N * 48;
  float* v1 = s1 + (size_t)N * 32;

  const int nodeBlocks = (N * 80 + 255) / 256;
  const int edgeBlocks = (E + 127) / 128;
  const int finBlocks  = (N + 255) / 256;

  fragpack_kernel<<<(147456 + 255) / 256, 256, 0, stream>>>(wr2, fhi, flo);
  mmat_kernel<<<1, 64, 0, stream>>>(dirs, wf);
  node_init_kernel<<<nodeBlocks, 256, 0, stream>>>(x, wins, winv, s0, v0, N);

  // layer 0: s0/v0 -> s1/v1
  selfmix_kernel<<<nodeBlocks, 256, 0, stream>>>(s0, v0, s1, v1, wscs, wscv, 0, N);
  edge_kernel<<<edgeBlocks, 256, 0, stream>>>(ei, ed, esh, s0, v0, s1, v1,
      wr1, br1, fhi, flo, br2, wpgs, wpgv, wlos, wlov, 0, E, N);
  // layer 1: s1/v1 -> s0/v0
  selfmix_kernel<<<nodeBlocks, 256, 0, stream>>>(s1, v1, s0, v0, wscs, wscv, 1, N);
  edge_kernel<<<edgeBlocks, 256, 0, stream>>>(ei, ed, esh, s1, v1, s0, v0,
      wr1, br1, fhi, flo, br2, wpgs, wpgv, wlos, wlov, 1, E, N);

  final_kernel<<<finBlocks, 256, 0, stream>>>(s0, v0, wos, wov, wf,
      (float*)d_out, N);
}

// Round 14
// 355.884 us; speedup vs baseline: 2.6433x; 1.8388x over previous
//
#include <hip/hip_runtime.h>

// ---------------- constants ----------------
#define CUTOFF_F     0.35f
#define PI_F         3.14159265358979323846f
#define SQRT3_F      1.7320508075688772f
#define INV_SQRT3_F  0.5773502691896258f
#define INV_SQRT_S_F 0.17677669529663687f   // 1/sqrt(32)
#define INV_SQRT_V_F 0.25f                  // 1/sqrt(16)
#define A_SC_F       0.14433756729740643f   // 1/sqrt(48)

// ws layout (floats): [0..12) M | fragHi | fragLo | node buffers | CSR | scratch
#define OFF_M      0
#define OFF_FRAGHI 16        // 147456 ushort = 73728 floats
#define OFF_FRAGLO 73744
#define OFF_NODE   147472

// LDS union (floats)
#define SH_H    0                 // 128*33 = 4224 (hext, stride 33)
#define SH_SJ   4224              // 32*128 = 4096
#define SH_VD   (4224+4096)       // 16*128 = 2048
#define SH_VJ   (4224+6144)       // 48*128 = 6144
#define SH_X    4224              // 128*81 = 10368 (aliases SJ/VD/VJ after B3)
#define SH_Y    (4224+12288)      // 4*128 = 512
#define SH_TOT  (4224+12288+512)  // 68096 B -> 2 blocks/CU (LDS-limited)

typedef __attribute__((ext_vector_type(8))) short bshort8;
typedef __attribute__((ext_vector_type(4))) float f32x4;

static __device__ __forceinline__ float b2f(unsigned short u) {
  union { unsigned int i; float f; } x; x.i = ((unsigned int)u) << 16; return x.f;
}
static __device__ __forceinline__ unsigned short f2b(float f) {
  union { float f; unsigned int i; } x; x.f = f;
  unsigned int i = x.i;
  return (unsigned short)((i + 0x7FFFu + ((i >> 16) & 1u)) >> 16);
}
// compensated bf16 product: 2-MFMA chain (residuals) + 1 independent MFMA
static __device__ __forceinline__ f32x4 mfma_c(bshort8 ah, bshort8 al, bshort8 bh, bshort8 bl) {
  f32x4 z = {0.f, 0.f, 0.f, 0.f};
  z = __builtin_amdgcn_mfma_f32_16x16x32_bf16(al, bh, z, 0, 0, 0);
  z = __builtin_amdgcn_mfma_f32_16x16x32_bf16(ah, bl, z, 0, 0, 0);
  f32x4 m = {0.f, 0.f, 0.f, 0.f};
  m = __builtin_amdgcn_mfma_f32_16x16x32_bf16(ah, bh, m, 0, 0, 0);
  return z + m;
}

// pack Wr2 into MFMA B-fragments, compensated bf16 (hi + lo residual)
__global__ __launch_bounds__(256) void fragpack_kernel(
    const float* __restrict__ wr2, unsigned short* __restrict__ fhi,
    unsigned short* __restrict__ flo)
{
  int idx = blockIdx.x * 256 + threadIdx.x;
  if (idx >= 147456) return;
  int i    = idx & 7;
  int lane = (idx >> 3) & 63;
  int tl   = idx >> 9;
  int t    = tl % 144;
  int layer = tl / 144;
  int c = (lane >> 4) * 8 + i;
  int j = t * 16 + (lane & 15);
  float w = wr2[((size_t)(layer * 32 + c)) * 2304 + j];
  unsigned short h = f2b(w);
  fhi[idx] = h;
  flo[idx] = f2b(w - b2f(h));
}

// M[c][k] = (1/256) * Y[:,c] . dirs[:,k]
__global__ void mmat_kernel(const float* __restrict__ dirs, float* __restrict__ wf) {
  int t = threadIdx.x;
  if (t >= 12) return;
  int c = t / 3, k = t - c * 3;
  float acc = 0.f;
  for (int p = 0; p < 256; ++p) {
    float dk = dirs[p * 3 + k];
    acc += (c == 0) ? dk : dirs[p * 3 + (c - 1)] * dk;
  }
  wf[OFF_M + t] = acc * ((c == 0) ? (1.0f / 256.0f) : (SQRT3_F / 256.0f));
}

__global__ __launch_bounds__(256) void node_init_kernel(
    const float* __restrict__ x, const float* __restrict__ wins,
    const float* __restrict__ winv,
    float* __restrict__ s0, float* __restrict__ v0, int N)
{
  int t = blockIdx.x * 256 + threadIdx.x;
  int n = t / 80; int slot = t - n * 80;
  if (n >= N) return;
  if (slot < 32) {
    float acc = 0.f;
    #pragma unroll
    for (int d = 0; d < 3; ++d) acc += x[n * 6 + d] * wins[d * 32 + slot];
    s0[n * 32 + slot] = acc * INV_SQRT3_F;
  } else {
    int j = slot - 32; int u = j / 3; int k = j - u * 3;
    v0[n * 48 + j] = x[n * 6 + 3 + k] * winv[u];
  }
}

__global__ __launch_bounds__(256) void selfmix_kernel(
    const float* __restrict__ sc, const float* __restrict__ vc,
    float* __restrict__ sn, float* __restrict__ vn,
    const float* __restrict__ wscs, const float* __restrict__ wscv,
    int layer, int N)
{
  int t = blockIdx.x * 256 + threadIdx.x;
  int n = t / 80; int slot = t - n * 80;
  if (n >= N) return;
  if (slot < 32) {
    const float* W = wscs + layer * 1024;
    float acc = 0.f;
    #pragma unroll
    for (int u = 0; u < 32; ++u) acc += sc[n * 32 + u] * W[u * 32 + slot];
    sn[n * 32 + slot] = acc * INV_SQRT_S_F;
  } else {
    int j = slot - 32; int w = j / 3; int k = j - w * 3;
    const float* W = wscv + layer * 256;
    float acc = 0.f;
    #pragma unroll
    for (int u = 0; u < 16; ++u) acc += vc[n * 48 + u * 3 + k] * W[u * 16 + w];
    vn[n * 48 + j] = acc * INV_SQRT_V_F;
  }
}

// ---------------- CSR build (per launch; ei is constant input) ----------------
__global__ __launch_bounds__(256) void zero_kernel(int* __restrict__ cnt, int N) {
  int i = blockIdx.x * 256 + threadIdx.x;
  if (i < N) cnt[i] = 0;
}
__global__ __launch_bounds__(256) void hist_kernel(
    const int* __restrict__ ei, int* __restrict__ cnt, int E, int N) {
  int e = blockIdx.x * 256 + threadIdx.x;
  if (e >= E) return;
  int d = ei[E + e]; d = (d < 0) ? 0 : (d >= N ? N - 1 : d);
  atomicAdd(&cnt[d], 1);
}
// single-block exclusive scan: off[0..N], off2 copy
__global__ __launch_bounds__(256) void scan_kernel(
    const int* __restrict__ cnt, int* __restrict__ off, int* __restrict__ off2, int N) {
  __shared__ int part[256];
  const int t = threadIdx.x;
  const int chunk = (N + 255) / 256;
  const int lo = t * chunk;
  const int hi = min(lo + chunk, N);
  int s = 0;
  for (int i = lo; i < hi; ++i) s += cnt[i];
  part[t] = s;
  __syncthreads();
  for (int d = 1; d < 256; d <<= 1) {
    int v = (t >= d) ? part[t - d] : 0;
    __syncthreads();
    part[t] += v;
    __syncthreads();
  }
  int run = (t == 0) ? 0 : part[t - 1];
  for (int i = lo; i < hi; ++i) {
    off[i] = run; off2[i] = run;
    run += cnt[i];
  }
  if (t == 255) off[N] = run;
}
__global__ __launch_bounds__(256) void pos_kernel(
    const int* __restrict__ ei, int* __restrict__ off2, int* __restrict__ pos,
    int E, int N) {
  int e = blockIdx.x * 256 + threadIdx.x;
  if (e >= E) return;
  int d = ei[E + e]; d = (d < 0) ? 0 : (d >= N ? N - 1 : d);
  pos[e] = atomicAdd(&off2[d], 1);
}

// ---------------- gather: sn/vn += segment-sum of scratch rows ----------------
__global__ __launch_bounds__(256) void gather_kernel(
    const int* __restrict__ off, const float* __restrict__ scr,
    float* __restrict__ sn, float* __restrict__ vn, int N) {
  int t = blockIdx.x * 256 + threadIdx.x;
  int n = t / 80; int slot = t - n * 80;
  if (n >= N) return;
  const int o0 = off[n], o1 = off[n + 1];
  float* dst = (slot < 32) ? &sn[(size_t)n * 32 + slot] : &vn[(size_t)n * 48 + slot - 32];
  float acc = *dst;
  for (int r = o0; r < o1; ++r) acc += scr[(size_t)r * 80 + slot];
  *dst = acc;
}

// ---------------- edge kernel: round-13 PASSING structure verbatim -----------
// Only the tail changed: plain f32x4 stores into scratch[pos[e]*80] (L2 line-
// coalesced, ~16MB eviction) instead of 4M write-through atomics (~128MB).
// Atomic fallback kept for scr==nullptr (ws too small).
__global__ __launch_bounds__(256, 1) void edge_kernel(
    const int* __restrict__ ei, const float* __restrict__ ed,
    const float* __restrict__ esh,
    const float* __restrict__ sc, const float* __restrict__ vc,
    float* __restrict__ sn, float* __restrict__ vn,
    const float* __restrict__ wr1, const float* __restrict__ br1,
    const unsigned short* __restrict__ wfh, const unsigned short* __restrict__ wfl,
    const float* __restrict__ br2,
    const float* __restrict__ wpgs, const float* __restrict__ wpgv,
    const float* __restrict__ wlos, const float* __restrict__ wlov,
    const int* __restrict__ pos, float* __restrict__ scr,
    int layer, int E, int N)
{
  __shared__ __align__(16) float sm[SH_TOT];

  const int tid  = threadIdx.x;
  const int lane = tid & 63;
  const int q    = tid >> 6;
  const int col  = lane & 15;
  const int quad = lane >> 4;
  const int wq8  = q * 8;
  const int wq4  = q * 4;
  const int ge0  = blockIdx.x * 128 + lane;
  const int ge1  = ge0 + 64;
  const bool ok0 = ge0 < E, ok1 = ge1 < E;
  const int eL0  = ok0 ? ge0 : E - 1;
  const int eL1  = ok1 ? ge1 : E - 1;
  int sn0 = ei[eL0];     sn0 = (sn0 < 0) ? 0 : (sn0 >= N ? N - 1 : sn0);
  int sn1 = ei[eL1];     sn1 = (sn1 < 0) ? 0 : (sn1 >= N ? N - 1 : sn1);
  int dn0 = ei[E + eL0]; dn0 = (dn0 < 0) ? 0 : (dn0 >= N ? N - 1 : dn0);
  int dn1 = ei[E + eL1]; dn1 = (dn1 < 0) ? 0 : (dn1 >= N ? N - 1 : dn1);
  const bool useScr = (scr != nullptr);
  const int p0 = useScr ? pos[eL0] : 0;
  const int p1 = useScr ? pos[eL1] : 0;
  const float y00 = esh[eL0*4+0], y0x = esh[eL0*4+1], y0y = esh[eL0*4+2], y0z = esh[eL0*4+3];
  const float y10 = esh[eL1*4+0], y1x = esh[eL1*4+1], y1y = esh[eL1*4+2], y1z = esh[eL1*4+3];

  // ---- stage h (wave-split over j, 2 edges/lane) ----
  {
    const float d0 = ed[eL0], d1 = ed[eL1];
    const float inv_w = 12.0f / CUTOFF_F;
    float cut0 = (d0 < CUTOFF_F) ? 0.5f * (__cosf(d0 * (PI_F / CUTOFF_F)) + 1.0f) : 0.0f;
    float cut1 = (d1 < CUTOFF_F) ? 0.5f * (__cosf(d1 * (PI_F / CUTOFF_F)) + 1.0f) : 0.0f;
    float rb0[6], rb1[6];
    #pragma unroll
    for (int r = 0; r < 6; ++r) {
      float z0 = (d0 - 0.07f * (float)r) * inv_w;
      float z1 = (d1 - 0.07f * (float)r) * inv_w;
      rb0[r] = __expf(-0.5f * z0 * z0) * cut0;
      rb1[r] = __expf(-0.5f * z1 * z1) * cut1;
    }
    const float* W1p = wr1 + layer * 192;
    const float* B1p = br1 + layer * 32;
    #pragma unroll
    for (int jj = 0; jj < 8; ++jj) {
      const int j = wq8 + jj;
      float z0 = B1p[j], z1 = z0;
      #pragma unroll
      for (int r = 0; r < 6; ++r) {
        const float wv = W1p[r * 32 + j];
        z0 += rb0[r] * wv; z1 += rb1[r] * wv;
      }
      sm[SH_H + lane * 33 + j]        = z0 / (1.0f + __expf(-z0));
      sm[SH_H + (lane + 64) * 33 + j] = z1 / (1.0f + __expf(-z1));
    }
  }
  // ---- stage sSj ----
  {
    const f32x4* pA = (const f32x4*)(sc + (size_t)sn0 * 32 + wq8);
    f32x4 a = pA[0], b = pA[1];
    #pragma unroll
    for (int i = 0; i < 4; ++i) {
      sm[SH_SJ + (wq8 + i) * 128 + lane]     = a[i];
      sm[SH_SJ + (wq8 + 4 + i) * 128 + lane] = b[i];
    }
    const f32x4* pB = (const f32x4*)(sc + (size_t)sn1 * 32 + wq8);
    a = pB[0]; b = pB[1];
    #pragma unroll
    for (int i = 0; i < 4; ++i) {
      sm[SH_SJ + (wq8 + i) * 128 + lane + 64]     = a[i];
      sm[SH_SJ + (wq8 + 4 + i) * 128 + lane + 64] = b[i];
    }
  }
  // ---- stage sVj + sVd ----
  {
    const f32x4* vp = (const f32x4*)(vc + (size_t)sn0 * 48 + wq4 * 3);
    f32x4 a = vp[0], b = vp[1], c = vp[2];
    float vt[12];
    #pragma unroll
    for (int i = 0; i < 4; ++i) { vt[i] = a[i]; vt[4+i] = b[i]; vt[8+i] = c[i]; }
    #pragma unroll
    for (int i = 0; i < 12; ++i) sm[SH_VJ + (wq4 * 3 + i) * 128 + lane] = vt[i];
    #pragma unroll
    for (int u = 0; u < 4; ++u)
      sm[SH_VD + (wq4 + u) * 128 + lane] =
          vt[u*3] * y0x + vt[u*3+1] * y0y + vt[u*3+2] * y0z;
    vp = (const f32x4*)(vc + (size_t)sn1 * 48 + wq4 * 3);
    a = vp[0]; b = vp[1]; c = vp[2];
    #pragma unroll
    for (int i = 0; i < 4; ++i) { vt[i] = a[i]; vt[4+i] = b[i]; vt[8+i] = c[i]; }
    #pragma unroll
    for (int i = 0; i < 12; ++i) sm[SH_VJ + (wq4 * 3 + i) * 128 + lane + 64] = vt[i];
    #pragma unroll
    for (int u = 0; u < 4; ++u)
      sm[SH_VD + (wq4 + u) * 128 + lane + 64] =
          vt[u*3] * y1x + vt[u*3+1] * y1y + vt[u*3+2] * y1z;
  }
  if (q == 0) {
    sm[SH_Y + 0*128 + lane] = y00;  sm[SH_Y + 1*128 + lane] = y0x;
    sm[SH_Y + 2*128 + lane] = y0y;  sm[SH_Y + 3*128 + lane] = y0z;
    sm[SH_Y + 0*128 + lane + 64] = y10;  sm[SH_Y + 1*128 + lane + 64] = y1x;
    sm[SH_Y + 2*128 + lane + 64] = y1y;  sm[SH_Y + 3*128 + lane + 64] = y1z;
  }
  __syncthreads();   // B1

  // ---- A-fragments for 2 M-tiles ----
  bshort8 a0h, a0l, a1h, a1l;
  #pragma unroll
  for (int i = 0; i < 8; ++i) {
    float h0 = sm[SH_H + (32*q + col) * 33 + quad * 8 + i];
    float h1 = sm[SH_H + (32*q + 16 + col) * 33 + quad * 8 + i];
    unsigned short hh0 = f2b(h0), hh1 = f2b(h1);
    a0h[i] = (short)hh0; a0l[i] = (short)f2b(h0 - b2f(hh0));
    a1h[i] = (short)hh1; a1l[i] = (short)f2b(h1 - b2f(hh1));
  }

  const bshort8* wbh = (const bshort8*)wfh + (size_t)layer * 144 * 64 + lane;
  const bshort8* wbl = (const bshort8*)wfl + (size_t)layer * 144 * 64 + lane;
  const float* br2L = br2 + (size_t)layer * 2304;
  const int eb0 = 32*q + quad * 4;
  const int eb1 = eb0 + 16;

  float accA0[8], accA1[8], accB0[8], accB1[8];
  float accC0[4], accC1[4], accD0[12], accD1[12];
  #pragma unroll
  for (int i = 0; i < 8; ++i) { accA0[i]=0.f; accA1[i]=0.f; accB0[i]=0.f; accB1[i]=0.f; }
  #pragma unroll
  for (int i = 0; i < 4; ++i) { accC0[i]=0.f; accC1[i]=0.f; }
  #pragma unroll
  for (int i = 0; i < 12; ++i) { accD0[i]=0.f; accD1[i]=0.f; }

  // ---- W1/W3 loop ----
  {
    bshort8 h0 = wbh[0*64],  l0 = wbl[0*64];
    bshort8 h1 = wbh[1*64],  l1 = wbl[1*64];
    bshort8 h2 = wbh[96*64], l2 = wbl[96*64];
    for (int u = 0; u < 32; ++u) {
      const bshort8 c0h=h0, c0l=l0, c1h=h1, c1l=l1, c2h=h2, c2l=l2;
      if (u < 31) {
        h0 = wbh[(size_t)(2*u+2)*64];  l0 = wbl[(size_t)(2*u+2)*64];
        h1 = wbh[(size_t)(2*u+3)*64];  l1 = wbl[(size_t)(2*u+3)*64];
        h2 = wbh[(size_t)(97+u)*64];   l2 = wbl[(size_t)(97+u)*64];
      }
      const float bb0 = br2L[(2*u)*16 + col];
      const float bb1 = br2L[(2*u+1)*16 + col];
      const float bb2 = br2L[(96+u)*16 + col];
      const f32x4 sj0 = *(const f32x4*)&sm[SH_SJ + u*128 + eb0];
      const f32x4 sj1 = *(const f32x4*)&sm[SH_SJ + u*128 + eb1];
      f32x4 t00 = mfma_c(a0h, a0l, c0h, c0l);
      f32x4 t01 = mfma_c(a1h, a1l, c0h, c0l);
      f32x4 t10 = mfma_c(a0h, a0l, c1h, c1l);
      f32x4 t11 = mfma_c(a1h, a1l, c1h, c1l);
      f32x4 t20 = mfma_c(a0h, a0l, c2h, c2l);
      f32x4 t21 = mfma_c(a1h, a1l, c2h, c2l);
      #pragma unroll
      for (int r = 0; r < 4; ++r) {
        accA0[r]   += sj0[r] * (t00[r] + bb0);
        accA1[r]   += sj1[r] * (t01[r] + bb0);
        accA0[4+r] += sj0[r] * (t10[r] + bb1);
        accA1[4+r] += sj1[r] * (t11[r] + bb1);
        accC0[r]   += sj0[r] * (t20[r] + bb2);
        accC1[r]   += sj1[r] * (t21[r] + bb2);
      }
    }
  }
  // ---- W2/W4 loop ----
  {
    bshort8 h0 = wbh[64*64],  l0 = wbl[64*64];
    bshort8 h1 = wbh[65*64],  l1 = wbl[65*64];
    bshort8 h2 = wbh[128*64], l2 = wbl[128*64];
    for (int u = 0; u < 16; ++u) {
      const bshort8 c0h=h0, c0l=l0, c1h=h1, c1l=l1, c2h=h2, c2l=l2;
      if (u < 15) {
        h0 = wbh[(size_t)(66+2*u)*64];  l0 = wbl[(size_t)(66+2*u)*64];
        h1 = wbh[(size_t)(67+2*u)*64];  l1 = wbl[(size_t)(67+2*u)*64];
        h2 = wbh[(size_t)(129+u)*64];   l2 = wbl[(size_t)(129+u)*64];
      }
      const float bb0 = br2L[(64+2*u)*16 + col];
      const float bb1 = br2L[(65+2*u)*16 + col];
      const float bb2 = br2L[(128+u)*16 + col];
      const f32x4 vd0 = *(const f32x4*)&sm[SH_VD + u*128 + eb0];
      const f32x4 vd1 = *(const f32x4*)&sm[SH_VD + u*128 + eb1];
      f32x4 t00 = mfma_c(a0h, a0l, c0h, c0l);
      f32x4 t01 = mfma_c(a1h, a1l, c0h, c0l);
      f32x4 t10 = mfma_c(a0h, a0l, c1h, c1l);
      f32x4 t11 = mfma_c(a1h, a1l, c1h, c1l);
      f32x4 t20 = mfma_c(a0h, a0l, c2h, c2l);
      f32x4 t21 = mfma_c(a1h, a1l, c2h, c2l);
      #pragma unroll
      for (int r = 0; r < 4; ++r) {
        accB0[r]   += vd0[r] * (t00[r] + bb0);
        accB1[r]   += vd1[r] * (t01[r] + bb0);
        accB0[4+r] += vd0[r] * (t10[r] + bb1);
        accB1[4+r] += vd1[r] * (t11[r] + bb1);
      }
      #pragma unroll
      for (int k = 0; k < 3; ++k) {
        const f32x4 vj0 = *(const f32x4*)&sm[SH_VJ + (u*3+k)*128 + eb0];
        const f32x4 vj1 = *(const f32x4*)&sm[SH_VJ + (u*3+k)*128 + eb1];
        #pragma unroll
        for (int r = 0; r < 4; ++r) {
          accD0[k*4+r] += vj0[r] * (t20[r] + bb2);
          accD1[k*4+r] += vj1[r] * (t21[r] + bb2);
        }
      }
    }
  }
  __syncthreads();   // B3

  // ---- messages into sX ----
  #pragma unroll
  for (int mt = 0; mt < 2; ++mt) {
    const int ebm = (mt == 0) ? eb0 : eb1;
    const float* aA = (mt == 0) ? accA0 : accA1;
    const float* aB = (mt == 0) ? accB0 : accB1;
    const float* aC = (mt == 0) ? accC0 : accC1;
    const float* aD = (mt == 0) ? accD0 : accD1;
    const f32x4 y0v  = *(const f32x4*)&sm[SH_Y + 0*128 + ebm];
    const f32x4 y1xv = *(const f32x4*)&sm[SH_Y + 1*128 + ebm];
    const f32x4 y1yv = *(const f32x4*)&sm[SH_Y + 2*128 + ebm];
    const f32x4 y1zv = *(const f32x4*)&sm[SH_Y + 3*128 + ebm];
    #pragma unroll
    for (int ch = 0; ch < 2; ++ch)
      #pragma unroll
      for (int r = 0; r < 4; ++r)
        sm[SH_X + (ebm + r) * 81 + ch*16 + col] =
            A_SC_F * (y0v[r] * aA[ch*4+r] + INV_SQRT3_F * aB[ch*4+r]);
    #pragma unroll
    for (int r = 0; r < 4; ++r) {
      sm[SH_X + (ebm + r)*81 + 32 + col*3 + 0] = A_SC_F * (aC[r]*y1xv[r] + y0v[r]*aD[0+r]);
      sm[SH_X + (ebm + r)*81 + 32 + col*3 + 1] = A_SC_F * (aC[r]*y1yv[r] + y0v[r]*aD[4+r]);
      sm[SH_X + (ebm + r)*81 + 32 + col*3 + 2] = A_SC_F * (aC[r]*y1zv[r] + y0v[r]*aD[8+r]);
    }
  }
  __syncthreads();   // B4

  // ---- pg phase ----
  float ps0[8], ps1[8], pt0[4], pt1[4];
  #pragma unroll
  for (int i = 0; i < 8; ++i) { ps0[i] = 0.f; ps1[i] = 0.f; }
  #pragma unroll
  for (int i = 0; i < 4; ++i) { pt0[i] = 0.f; pt1[i] = 0.f; }
  {
    const float* Wp = wpgs + layer * 1536;
    #pragma unroll
    for (int u = 0; u < 32; ++u) {
      const float m0 = sm[SH_X + lane * 81 + u];
      const float m1 = sm[SH_X + (lane + 64) * 81 + u];
      #pragma unroll
      for (int jj = 0; jj < 8; ++jj) {
        const float wv = Wp[u * 48 + wq8 + jj];
        ps0[jj] += m0 * wv; ps1[jj] += m1 * wv;
      }
      #pragma unroll
      for (int wi = 0; wi < 4; ++wi) {
        const float wv = Wp[u * 48 + 32 + wq4 + wi];
        pt0[wi] += m0 * wv; pt1[wi] += m1 * wv;
      }
    }
  }
  float pv0[12], pv1[12];
  #pragma unroll
  for (int i = 0; i < 12; ++i) { pv0[i] = 0.f; pv1[i] = 0.f; }
  {
    const float* Wp = wpgv + layer * 256;
    #pragma unroll
    for (int u = 0; u < 16; ++u) {
      const float a0 = sm[SH_X + lane*81 + 32 + u*3 + 0];
      const float a1 = sm[SH_X + lane*81 + 32 + u*3 + 1];
      const float a2 = sm[SH_X + lane*81 + 32 + u*3 + 2];
      const float b0 = sm[SH_X + (lane+64)*81 + 32 + u*3 + 0];
      const float b1 = sm[SH_X + (lane+64)*81 + 32 + u*3 + 1];
      const float b2 = sm[SH_X + (lane+64)*81 + 32 + u*3 + 2];
      #pragma unroll
      for (int wi = 0; wi < 4; ++wi) {
        const float wv = Wp[u * 16 + wq4 + wi];
        pv0[wi*3+0] += a0*wv; pv0[wi*3+1] += a1*wv; pv0[wi*3+2] += a2*wv;
        pv1[wi*3+0] += b0*wv; pv1[wi*3+1] += b1*wv; pv1[wi*3+2] += b2*wv;
      }
    }
  }
  __syncthreads();   // B5

  #pragma unroll
  for (int jj = 0; jj < 8; ++jj) {
    const float t0 = ps0[jj] * INV_SQRT_S_F;
    const float t1 = ps1[jj] * INV_SQRT_S_F;
    sm[SH_X + lane * 81 + wq8 + jj]        = t0 / (1.0f + __expf(-t0));
    sm[SH_X + (lane + 64) * 81 + wq8 + jj] = t1 / (1.0f + __expf(-t1));
  }
  #pragma unroll
  for (int wi = 0; wi < 4; ++wi) {
    const float g0 = 1.0f / (1.0f + __expf(-pt0[wi] * INV_SQRT_S_F));
    const float g1 = 1.0f / (1.0f + __expf(-pt1[wi] * INV_SQRT_S_F));
    #pragma unroll
    for (int k = 0; k < 3; ++k) {
      sm[SH_X + lane * 81 + 32 + (wq4 + wi)*3 + k]        = g0 * pv0[wi*3+k] * INV_SQRT_V_F;
      sm[SH_X + (lane + 64) * 81 + 32 + (wq4 + wi)*3 + k] = g1 * pv1[wi*3+k] * INV_SQRT_V_F;
    }
  }
  __syncthreads();   // B6

  // ---- o = g @ Wlo (w-split) ----
  float os0[8], os1[8];
  #pragma unroll
  for (int i = 0; i < 8; ++i) { os0[i] = 0.f; os1[i] = 0.f; }
  {
    const float* Wp = wlos + layer * 1024;
    #pragma unroll
    for (int u = 0; u < 32; ++u) {
      const float g0 = sm[SH_X + lane * 81 + u];
      const float g1 = sm[SH_X + (lane + 64) * 81 + u];
      #pragma unroll
      for (int wi = 0; wi < 8; ++wi) {
        const float wv = Wp[u * 32 + wq8 + wi];
        os0[wi] += g0 * wv; os1[wi] += g1 * wv;
      }
    }
  }
  float ov0[12], ov1[12];
  #pragma unroll
  for (int i = 0; i < 12; ++i) { ov0[i] = 0.f; ov1[i] = 0.f; }
  {
    const float* Wp = wlov + layer * 256;
    #pragma unroll
    for (int u = 0; u < 16; ++u) {
      const float a0 = sm[SH_X + lane*81 + 32 + u*3 + 0];
      const float a1 = sm[SH_X + lane*81 + 32 + u*3 + 1];
      const float a2 = sm[SH_X + lane*81 + 32 + u*3 + 2];
      const float b0 = sm[SH_X + (lane+64)*81 + 32 + u*3 + 0];
      const float b1 = sm[SH_X + (lane+64)*81 + 32 + u*3 + 1];
      const float b2 = sm[SH_X + (lane+64)*81 + 32 + u*3 + 2];
      #pragma unroll
      for (int wi = 0; wi < 4; ++wi) {
        const float wv = Wp[u * 16 + wq4 + wi];
        ov0[wi*3+0] += a0*wv; ov0[wi*3+1] += a1*wv; ov0[wi*3+2] += a2*wv;
        ov1[wi*3+0] += b0*wv; ov1[wi*3+1] += b1*wv; ov1[wi*3+2] += b2*wv;
      }
    }
  }

  if (useScr) {
    // plain stores into CSR-slot rows: 320 B contiguous per edge, line-coalesced
    if (ok0) {
      float* row = scr + (size_t)p0 * 80;
      f32x4 v;
      v = f32x4{os0[0], os0[1], os0[2], os0[3]} * INV_SQRT_S_F; *(f32x4*)(row + wq8) = v;
      v = f32x4{os0[4], os0[5], os0[6], os0[7]} * INV_SQRT_S_F; *(f32x4*)(row + wq8 + 4) = v;
      float* rv = row + 32 + wq4 * 3;
      v = f32x4{ov0[0], ov0[1], ov0[2], ov0[3]} * INV_SQRT_V_F; *(f32x4*)(rv) = v;
      v = f32x4{ov0[4], ov0[5], ov0[6], ov0[7]} * INV_SQRT_V_F; *(f32x4*)(rv + 4) = v;
      v = f32x4{ov0[8], ov0[9], ov0[10], ov0[11]} * INV_SQRT_V_F; *(f32x4*)(rv + 8) = v;
    }
    if (ok1) {
      float* row = scr + (size_t)p1 * 80;
      f32x4 v;
      v = f32x4{os1[0], os1[1], os1[2], os1[3]} * INV_SQRT_S_F; *(f32x4*)(row + wq8) = v;
      v = f32x4{os1[4], os1[5], os1[6], os1[7]} * INV_SQRT_S_F; *(f32x4*)(row + wq8 + 4) = v;
      float* rv = row + 32 + wq4 * 3;
      v = f32x4{ov1[0], ov1[1], ov1[2], ov1[3]} * INV_SQRT_V_F; *(f32x4*)(rv) = v;
      v = f32x4{ov1[4], ov1[5], ov1[6], ov1[7]} * INV_SQRT_V_F; *(f32x4*)(rv + 4) = v;
      v = f32x4{ov1[8], ov1[9], ov1[10], ov1[11]} * INV_SQRT_V_F; *(f32x4*)(rv + 8) = v;
    }
  } else {
    if (ok0) {
      float* sd = sn + (size_t)dn0 * 32 + wq8;
      #pragma unroll
      for (int wi = 0; wi < 8; ++wi) unsafeAtomicAdd(&sd[wi], os0[wi] * INV_SQRT_S_F);
      float* vd = vn + (size_t)dn0 * 48 + wq4 * 3;
      #pragma unroll
      for (int j = 0; j < 12; ++j) unsafeAtomicAdd(&vd[j], ov0[j] * INV_SQRT_V_F);
    }
    if (ok1) {
      float* sd = sn + (size_t)dn1 * 32 + wq8;
      #pragma unroll
      for (int wi = 0; wi < 8; ++wi) unsafeAtomicAdd(&sd[wi], os1[wi] * INV_SQRT_S_F);
      float* vd = vn + (size_t)dn1 * 48 + wq4 * 3;
      #pragma unroll
      for (int j = 0; j < 12; ++j) unsafeAtomicAdd(&vd[j], ov1[j] * INV_SQRT_V_F);
    }
  }
}

// out[n,k] = coeffs[n] @ M  — FP32 OUTPUT
__global__ __launch_bounds__(256) void final_kernel(
    const float* __restrict__ s0, const float* __restrict__ v0,
    const float* __restrict__ wos, const float* __restrict__ wov,
    const float* __restrict__ wf, float* __restrict__ out, int N)
{
  int n = blockIdx.x * 256 + threadIdx.x;
  if (n >= N) return;
  float cs = 0.f;
  #pragma unroll
  for (int u = 0; u < 32; ++u) cs += s0[n * 32 + u] * wos[u];
  cs *= INV_SQRT_S_F;
  float cv0 = 0.f, cv1 = 0.f, cv2 = 0.f;
  #pragma unroll
  for (int u = 0; u < 16; ++u) {
    const float wv = wov[u];
    cv0 += v0[n * 48 + u * 3 + 0] * wv;
    cv1 += v0[n * 48 + u * 3 + 1] * wv;
    cv2 += v0[n * 48 + u * 3 + 2] * wv;
  }
  cv0 *= INV_SQRT_V_F; cv1 *= INV_SQRT_V_F; cv2 *= INV_SQRT_V_F;
  #pragma unroll
  for (int k = 0; k < 3; ++k) {
    out[n * 3 + k] = cs  * wf[OFF_M + k]
                   + cv0 * wf[OFF_M + 3 + k]
                   + cv1 * wf[OFF_M + 6 + k]
                   + cv2 * wf[OFF_M + 9 + k];
  }
}

extern "C" void kernel_launch(void* const* d_in, const int* in_sizes, int n_in,
                              void* d_out, int out_size, void* d_ws, size_t ws_size,
                              hipStream_t stream)
{
  (void)n_in; (void)out_size;
  const float* x    = (const float*)d_in[0];
  const int*   ei   = (const int*)d_in[1];
  const float* ed   = (const float*)d_in[2];
  const float* esh  = (const float*)d_in[3];
  const float* dirs = (const float*)d_in[4];
  const float* wins = (const float*)d_in[5];
  const float* winv = (const float*)d_in[6];
  const float* wscs = (const float*)d_in[7];
  const float* wscv = (const float*)d_in[8];
  const float* wr1  = (const float*)d_in[9];
  const float* br1  = (const float*)d_in[10];
  const float* wr2  = (const float*)d_in[11];
  const float* br2  = (const float*)d_in[12];
  const float* wpgs = (const float*)d_in[13];
  const float* wpgv = (const float*)d_in[14];
  const float* wlos = (const float*)d_in[15];
  const float* wlov = (const float*)d_in[16];
  const float* wos  = (const float*)d_in[17];
  const float* wov  = (const float*)d_in[18];

  const int N = in_sizes[0] / 6;
  const int E = in_sizes[1] / 2;

  float* wf = (float*)d_ws;
  unsigned short* fhi = (unsigned short*)(wf + OFF_FRAGHI);
  unsigned short* flo = (unsigned short*)(wf + OFF_FRAGLO);
  float* s0 = wf + OFF_NODE;
  float* v0 = s0 + (size_t)N * 32;
  float* s1 = v0 + (size_t)N * 48;
  float* v1 = s1 + (size_t)N * 32;

  // CSR + scratch region after node buffers
  int*   cnt  = (int*)(v1 + (size_t)N * 48);
  int*   off  = cnt + N;
  int*   off2 = off + (N + 1);
  int*   pos  = off2 + (N + 1);
  size_t intsEnd = (size_t)(OFF_NODE) + (size_t)N * 160 + (size_t)(3 * N + 2 + E);
  size_t scrOff  = (intsEnd + 3) & ~(size_t)3;       // 16B-align scratch
  float* scr  = wf + scrOff;
  size_t needFloats = scrOff + (size_t)E * 80;
  const bool useScr = (ws_size >= needFloats * 4);
  float* scrArg = useScr ? scr : nullptr;

  const int nodeBlocks = (N * 80 + 255) / 256;
  const int edgeBlocks = (E + 127) / 128;
  const int finBlocks  = (N + 255) / 256;
  const int eBlocks256 = (E + 255) / 256;
  const int nBlocks256 = (N + 255) / 256;

  fragpack_kernel<<<(147456 + 255) / 256, 256, 0, stream>>>(wr2, fhi, flo);
  mmat_kernel<<<1, 64, 0, stream>>>(dirs, wf);
  node_init_kernel<<<nodeBlocks, 256, 0, stream>>>(x, wins, winv, s0, v0, N);

  if (useScr) {  // build CSR once per launch (ei constant)
    zero_kernel<<<nBlocks256, 256, 0, stream>>>(cnt, N);
    hist_kernel<<<eBlocks256, 256, 0, stream>>>(ei, cnt, E, N);
    scan_kernel<<<1, 256, 0, stream>>>(cnt, off, off2, N);
    pos_kernel<<<eBlocks256, 256, 0, stream>>>(ei, off2, pos, E, N);
  }

  // layer 0: s0/v0 -> s1/v1
  selfmix_kernel<<<nodeBlocks, 256, 0, stream>>>(s0, v0, s1, v1, wscs, wscv, 0, N);
  edge_kernel<<<edgeBlocks, 256, 0, stream>>>(ei, ed, esh, s0, v0, s1, v1,
      wr1, br1, fhi, flo, br2, wpgs, wpgv, wlos, wlov, pos, scrArg, 0, E, N);
  if (useScr)
    gather_kernel<<<nodeBlocks, 256, 0, stream>>>(off, scr, s1, v1, N);

  // layer 1: s1/v1 -> s0/v0
  selfmix_kernel<<<nodeBlocks, 256, 0, stream>>>(s1, v1, s0, v0, wscs, wscv, 1, N);
  edge_kernel<<<edgeBlocks, 256, 0, stream>>>(ei, ed, esh, s1, v1, s0, v0,
      wr1, br1, fhi, flo, br2, wpgs, wpgv, wlos, wlov, pos, scrArg, 1, E, N);
  if (useScr)
    gather_kernel<<<nodeBlocks, 256, 0, stream>>>(off, scr, s0, v0, N);

  final_kernel<<<finBlocks, 256, 0, stream>>>(s0, v0, wos, wov, wf,
      (float*)d_out, N);
}